// Round 7
// baseline (170.549 us; speedup 1.0000x reference)
//
#include <hip/hip_runtime.h>

// LCSA: dilated local-window self-attention.
// B=2, L=1024, D=512, H=8, HEAD_W=64, KERNEL=16, dilations {1,1,2,2,4,4,8,8},
// MODE=forward -> src(l,k) = l - (15-k)*dil, zero-padded outside [0,L).
//
// R16: 64x128 per-wave tile in gemm_bf16 (LDS-bytes-per-FLOP attack).
//   R10-R15 all pinned at MfmaUtil 23-25% with a 64x64 wave tile: 8KB
//   ds_read + 4KB gl_lds-write per wave-iter at ~85 B/cyc/CU saturates the
//   LDS pipe (the invariant across all six null results). Now: block
//   128x256, 4 waves of 64x128 -> 12 ds_reads per 32 MFMA (2.67 vs 2.0),
//   total LDS traffic 1.62 -> 1.22 GB (-25%). R15's counted-vmcnt 3-buf
//   schedule kept verbatim (6 loads/stage -> vmcnt(6)), XCD-chunked remap
//   (1056 = 8*132, m-fastest), same XOR swizzle. 72KB LDS -> 2 blk/CU,
//   VGPR ~206 (launch_bounds (256,2)).
// attn_bf16: TWO-PHASE register-resident gather, panel layout (R14).
// gemm_out:  counted-vmcnt 3-buf (R15).
// cvt_swz:   fp32->bf16 + per-row XOR chunk swizzle (unchanged).
// Fallback:  round-1 fp32 path (8 MB ws).

#define BD 2
#define LL 1024
#define DM 512
#define HH 8
#define KT 16
#define HW 64

#define NQKV 16896          // legacy total: 512 q + 8192 k + 8192 v

typedef unsigned short u16;
typedef unsigned int u32;
typedef __bf16 bf16x8 __attribute__((ext_vector_type(8)));
typedef float f32x4 __attribute__((ext_vector_type(4)));
typedef unsigned short ushort4v __attribute__((ext_vector_type(4)));
typedef unsigned short ushort8v __attribute__((ext_vector_type(8)));

__constant__ int c_dil[8] = {1, 1, 2, 2, 4, 4, 8, 8};

__device__ __forceinline__ float bf2f(u16 u) {
    return __builtin_bit_cast(float, (u32)u << 16);
}
__device__ __forceinline__ u16 f2bf(float f) {   // round-to-nearest-even
    u32 u = __builtin_bit_cast(u32, f);
    return (u16)((u + 0x7fffu + ((u >> 16) & 1u)) >> 16);
}

// async global->LDS, 16 B per lane; lds dest must be (uniform base + lane*16)
__device__ __forceinline__ void gl_lds16(const u16* g, u16* l) {
    __builtin_amdgcn_global_load_lds(
        (__attribute__((address_space(1))) void*)g,
        (__attribute__((address_space(3))) void*)l, 16, 0, 0);
}

// raw workgroup barrier with compiler memory fences (proven in R11/R15)
__device__ __forceinline__ void bar() {
    asm volatile("" ::: "memory");
    __builtin_amdgcn_s_barrier();
    asm volatile("" ::: "memory");
}

// ===========================================================================
// Fused qkv projection GEMM, 64x128 per-wave, counted-vmcnt 3-buf pipeline.
// A(2048x512) * [Wq|Wk|Wv]^T + bias -> qb (2048x512) and kvb panels.
// kvb panel p = ((reg*8 + h)*16 + kslot)*2 + b, 65536 u16 each (1024x64).
// Block tile 128x256, BK=32, 4 waves (2m x 2n, 64x128 out each), 16x16x32
// MFMA, swizzled A/B, LDS 72KB (3 bufs) -> 2 blocks/CU. Grid 1056 linear.
//
// Block remap: wg = (bid&7)*132 + (bid>>3) (bijective, 1056 = 8*132),
//   m0 = (wg&15)*128 (fastest within XCD), n0 = (wg>>4)*256.
//
// Pipeline (6 gl_lds16 per stage): prologue stages tiles 0,1; vmcnt(6);
//   iter t: STG(t+2) (t<14); 12 ds_read; 32 MFMA; vmcnt(6) (t<14, leaves
//   t+2's 6 in flight) / vmcnt(0) (t==14); barrier.
// ===========================================================================
__global__ __launch_bounds__(256, 2) void gemm_bf16(
    const u16* __restrict__ A, const u16* __restrict__ Bm,
    const float* __restrict__ bq, const float* __restrict__ bk,
    const float* __restrict__ bv,
    u16* __restrict__ qb, u16* __restrict__ kvb)
{
    // XCD-chunked bijective remap (8 XCDs, 1056 = 8*132 blocks)
    const int bid = blockIdx.x;
    const int wg  = (bid & 7) * 132 + (bid >> 3);
    const int m0  = (wg & 15) << 7;     // m fastest within an XCD
    const int n0  = (wg >> 4) << 8;     // 66 n-tiles of 256

    __shared__ u16 As[3][128 * 32];     // 3 x 8 KB
    __shared__ u16 Bs[3][256 * 32];     // 3 x 16 KB

    const int tid  = threadIdx.x;
    const int wid  = tid >> 6, lane = tid & 63;
    const int wm   = wid >> 1;          // 0..1  (64-row band)
    const int wn   = wid & 1;           // 0..1  (128-col band)
    const int lr = lane & 15;
    const int qg = lane >> 4;
    const int ksw = ((qg ^ ((lr >> 1) & 3)) << 3);   // swizzled chunk

    const int r0 = tid >> 2;            // staging row 0..63
    const int cc = (tid & 3) << 3;      // staging k-offset (elements)
    const u16* Ag = A  + (size_t)(m0 + r0) * DM + cc;
    const u16* Bg = Bm + (size_t)(n0 + r0) * DM + cc;
    u16* lA = &As[0][0] + tid * 8;
    u16* lB = &Bs[0][0] + tid * 8;

    // stage k-tile t2 (32 wide) into buffer c (6 loads/thread)
#define STG(t2, c) do {                                                    \
        const int ko_ = (t2) << 5;                                         \
        gl_lds16(Ag + ko_,                   lA + (c) * 4096);             \
        gl_lds16(Ag + ko_ + (size_t)64*DM,   lA + (c) * 4096 + 2048);      \
        gl_lds16(Bg + ko_,                   lB + (c) * 8192);             \
        gl_lds16(Bg + ko_ + (size_t)64*DM,   lB + (c) * 8192 + 2048);      \
        gl_lds16(Bg + ko_ + (size_t)128*DM,  lB + (c) * 8192 + 4096);     \
        gl_lds16(Bg + ko_ + (size_t)192*DM,  lB + (c) * 8192 + 6144);     \
    } while (0)

    f32x4 acc[4][8];
#pragma unroll
    for (int i = 0; i < 4; ++i)
#pragma unroll
        for (int j = 0; j < 8; ++j) acc[i][j] = (f32x4){0.f, 0.f, 0.f, 0.f};

    STG(0, 0);
    STG(1, 1);
    asm volatile("s_waitcnt vmcnt(6)" ::: "memory");   // tile 0 landed
    bar();

#pragma unroll
    for (int t = 0; t < 16; ++t) {
        const int cur = t % 3;                         // unrolled -> literal
        if (t < 14) STG(t + 2, (t + 2) % 3);           // 2-deep prefetch

        bf16x8 af[4], bfr[8];
#pragma unroll
        for (int i = 0; i < 4; ++i)
            af[i] = *(const bf16x8*)
                &As[cur][((wm << 6) + (i << 4) + lr) * 32 + ksw];
#pragma unroll
        for (int j = 0; j < 8; ++j)
            bfr[j] = *(const bf16x8*)
                &Bs[cur][((wn << 7) + (j << 4) + lr) * 32 + ksw];
#pragma unroll
        for (int i = 0; i < 4; ++i)
#pragma unroll
            for (int j = 0; j < 8; ++j)
                acc[i][j] = __builtin_amdgcn_mfma_f32_16x16x32_bf16(
                    af[i], bfr[j], acc[i][j], 0, 0, 0);

        // counted wait: tile t+1 resident, t+2's loads stay in flight
        if (t < 14)
            asm volatile("s_waitcnt vmcnt(6)" ::: "memory");
        else if (t == 14)
            asm volatile("s_waitcnt vmcnt(0)" ::: "memory");
        if (t < 15) bar();
    }
#undef STG

    if (n0 < 512) {
        // ---- q region (n-tiles 0,1): qb[row][512] ----
#pragma unroll
        for (int i = 0; i < 4; ++i) {
            const int rowb = m0 + (wm << 6) + (i << 4) + (qg << 2);
#pragma unroll
            for (int j = 0; j < 8; ++j) {
                const int col = n0 + (wn << 7) + (j << 4) + lr;
                const float bs = bq[col];
#pragma unroll
                for (int r = 0; r < 4; ++r)
                    qb[(size_t)(rowb + r) * 512 + col] =
                        f2bf(acc[i][j][r] + bs);
            }
        }
    } else {
        // ---- k/v region: kvb panel ((reg*8+h)*16+kslot)*2+b, [l][64] ----
        const int reg = (n0 >= 8704);
        const float* bias = reg ? bv : bk;
        const int t0  = n0 - (reg ? 8704 : 512);   // region-local, 256-aligned
        const int h   = t0 >> 10;                  // head (1024 cols/head)
        const int pb  = ((reg << 3) + h) << 4;     // (reg*8+h)*16
#pragma unroll
        for (int i = 0; i < 4; ++i) {
            const int rowb = m0 + (wm << 6) + (i << 4) + (qg << 2);
#pragma unroll
            for (int j = 0; j < 8; ++j) {
                const int tcol  = (t0 & 1023) + (wn << 7) + (j << 4) + lr;
                const int kslot = tcol >> 6;
                const int oo    = tcol & 63;
                const float bs  = bias[(h << 10) + tcol];
#pragma unroll
                for (int r = 0; r < 4; ++r) {
                    const int row = rowb + r;
                    const int bb  = row >> 10, l2 = row & 1023;
                    kvb[((size_t)(((pb + kslot) << 1) + bb) << 16)
                        + (l2 << 6) + oo] = f2bf(acc[i][j][r] + bs);
                }
            }
        }
    }
}

// ===========================================================================
// Output projection: out(2048x512 fp32) = attnb(2048x512 swz) * Wo^T(512x512
// swz) + bo. 64x64 tiles, grid (8,32) = 256 blocks, 4 waves (16x64 each).
// Counted-vmcnt 3-buffer pipeline (R15).
// ===========================================================================
__global__ __launch_bounds__(256, 4) void gemm_out(
    const u16* __restrict__ A, const u16* __restrict__ Bm,
    const float* __restrict__ bias, float* __restrict__ C)
{
    __shared__ u16 As[3][64 * 32];      // 3 x 4 KB
    __shared__ u16 Bs[3][64 * 32];      // 3 x 4 KB

    const int tid  = threadIdx.x;
    const int wave = tid >> 6, lane = tid & 63;
    const int m0 = blockIdx.y << 6, n0 = blockIdx.x << 6;
    const int r0 = tid >> 2, cc = (tid & 3) << 3;
    const int mw = wave << 4;           // wave's 16-row band
    const int lr = lane & 15, qg = lane >> 4;
    const int ksw = ((qg ^ ((lr >> 1) & 3)) << 3);

    const u16* Ag = A  + (size_t)(m0 + r0) * DM + cc;
    const u16* Bg = Bm + (size_t)(n0 + r0) * DM + cc;
    u16* lA = &As[0][0] + tid * 8;
    u16* lB = &Bs[0][0] + tid * 8;

#define STG(t2, c) do {                                                    \
        const int ko_ = (t2) << 5;                                         \
        gl_lds16(Ag + ko_, lA + (c) * 2048);                               \
        gl_lds16(Bg + ko_, lB + (c) * 2048);                               \
    } while (0)

    f32x4 acc[4];
#pragma unroll
    for (int j = 0; j < 4; ++j) acc[j] = (f32x4){0.f, 0.f, 0.f, 0.f};

    STG(0, 0);
    STG(1, 1);
    asm volatile("s_waitcnt vmcnt(2)" ::: "memory");   // tile 0 landed
    bar();

#pragma unroll
    for (int t = 0; t < 16; ++t) {
        const int cur = t % 3;
        if (t < 14) STG(t + 2, (t + 2) % 3);

        bf16x8 af = *(const bf16x8*)&As[cur][(mw + lr) * 32 + ksw];
#pragma unroll
        for (int j = 0; j < 4; ++j) {
            bf16x8 bfr = *(const bf16x8*)&Bs[cur][((j << 4) + lr) * 32 + ksw];
            acc[j] = __builtin_amdgcn_mfma_f32_16x16x32_bf16(af, bfr, acc[j], 0, 0, 0);
        }

        if (t < 14)
            asm volatile("s_waitcnt vmcnt(2)" ::: "memory");
        else if (t == 14)
            asm volatile("s_waitcnt vmcnt(0)" ::: "memory");
        if (t < 15) bar();
    }
#undef STG

    // C row = m0+mw+4qg+r, col = n0+16j+lr
#pragma unroll
    for (int j = 0; j < 4; ++j) {
        const int col = n0 + (j << 4) + lr;
        const float bs = bias[col];
#pragma unroll
        for (int r = 0; r < 4; ++r)
            C[(size_t)(m0 + mw + (qg << 2) + r) * DM + col] = acc[j][r] + bs;
    }
}

// ===========================================================================
// fp32 -> bf16 + swizzle. One thread per 8-elem chunk: 32B read, 16B write,
// both coalesced (the XOR permutes chunks within a 64B line).
// Chunks (row*64): x 131072 | [Wq|Wk|Wv] 1081344 | Wo 32768
// Total 1245184 = 4864 blocks x 256.
// ===========================================================================
__global__ void cvt_swz(const float* __restrict__ x,  const float* __restrict__ Wq,
                        const float* __restrict__ Wk, const float* __restrict__ Wv,
                        const float* __restrict__ Wo,
                        u16* __restrict__ xb, u16* __restrict__ wb,
                        u16* __restrict__ wob)
{
    const int i = blockIdx.x * 256 + threadIdx.x;
    const float* src; u16* dst; int t;
    if (i < 131072) {
        t = i;
        src = x;  dst = xb;
    } else if (i < 1212416) {
        t = i - 131072;
        const int row = t >> 6;
        if      (row <  512) src = Wq;
        else if (row < 8704) src = Wk - (size_t)512 * DM;
        else                 src = Wv - (size_t)8704 * DM;
        dst = wb;
    } else {
        t = i - 1212416;
        src = Wo; dst = wob;
    }
    const int row = t >> 6;              // 64 chunks per row
    const int c8  = t & 63;              // output chunk within row
    const int s   = (row >> 1) & 3;
    const int oc  = (c8 & ~3) | ((c8 & 3) ^ s);   // source chunk
    const float* p = src + (size_t)row * DM + (oc << 3);
    float4 v0 = *(const float4*)p;
    float4 v1 = *(const float4*)(p + 4);
    ushort8v o = { f2bf(v0.x), f2bf(v0.y), f2bf(v0.z), f2bf(v0.w),
                   f2bf(v1.x), f2bf(v1.y), f2bf(v1.z), f2bf(v1.w) };
    *(ushort8v*)(dst + (size_t)row * DM + (c8 << 3)) = o;
}

// ===========================================================================
// attention gather, TWO-PHASE register-resident, panel layout (R14).
// 256 thr = 32 l's x 8 o-groups, grid = B*H*(L/32) = 512.
// K-load for kslot k: kvb panel ((h*16+k)*2+b) + src*64 + j*8 -> per-wave
// request = 8 lanes x 16B contiguous (128B), 8 l-groups at dil*128B stride.
// ===========================================================================
__global__ __launch_bounds__(256, 4) void attn_bf16(
    const u16* __restrict__ qb,     // (B*L, 512) bf16
    const u16* __restrict__ kvb,    // panels, see gemm_bf16
    const float* __restrict__ bk,   // (H,K,64) fp32
    const float* __restrict__ bv,
    u16* __restrict__ attnb)        // (B,L,512) bf16 swizzled
{
    const int tid = threadIdx.x;
    const int j  = tid & 7;          // o-group (8 o's)
    const int ll = tid >> 3;         // 0..31
    const int bid = blockIdx.x;
    const int h = bid & 7;
    const int t = (bid >> 3) & 31;
    const int b = bid >> 8;
    const int l = (t << 5) + ll;
    const int dil = c_dil[h];

    const int hko = h * (KT * HW);   // bias head offset

    float qf[8];
    {
        ushort8v qv = *(const ushort8v*)(qb + (size_t)(b * LL + l) * 512
                                         + h * HW + (j << 3));
#pragma unroll
        for (int z = 0; z < 8; ++z) qf[z] = bf2f(qv[z]);
    }

    // panel bases: K panel p = (h*16+k)*2+b, V panel p = ((8+h)*16+k)*2+b
    const u16* kbase = kvb + ((size_t)(((h << 4) << 1) + b) << 16) + (j << 3);
    const u16* vbase = kbase + ((size_t)(8 << 4) << 17);   // +8*16 panels *2*65536

    // ---- phase 1: all k loads in flight, then logits ----
    ushort8v kr[KT];
#pragma unroll
    for (int k = 0; k < KT; ++k) {
        const int src = l - (KT - 1 - k) * dil;
        if (src >= 0)
            kr[k] = *(const ushort8v*)(kbase + ((size_t)k << 17) + (src << 6));
    }

    float lg[KT];
#pragma unroll
    for (int k = 0; k < KT; ++k) {
        const int src = l - (KT - 1 - k) * dil;
        float p = 0.f;
        if (src >= 0) {
#pragma unroll
            for (int z = 0; z < 8; ++z) p += qf[z] * bf2f(kr[k][z]);
        } else {
            const float* bkp = bk + hko + k * HW + (j << 3);
#pragma unroll
            for (int z = 0; z < 8; ++z) p += qf[z] * bkp[z];
        }
        p += __shfl_xor(p, 1);
        p += __shfl_xor(p, 2);
        p += __shfl_xor(p, 4);
        lg[k] = p;
    }

    // ---- softmax in registers ----
    float m = lg[0];
#pragma unroll
    for (int k = 1; k < KT; ++k) m = fmaxf(m, lg[k]);
    float s = 0.f;
#pragma unroll
    for (int k = 0; k < KT; ++k) { lg[k] = __expf(lg[k] - m); s += lg[k]; }
    const float inv = 1.f / s;

    // ---- phase 2: all v loads in flight, weighted accumulate ----
    ushort8v vr[KT];
#pragma unroll
    for (int k = 0; k < KT; ++k) {
        const int src = l - (KT - 1 - k) * dil;
        if (src >= 0)
            vr[k] = *(const ushort8v*)(vbase + ((size_t)k << 17) + (src << 6));
    }

    float acc[8];
#pragma unroll
    for (int z = 0; z < 8; ++z) acc[z] = 0.f;
#pragma unroll
    for (int k = 0; k < KT; ++k) {
        const int src = l - (KT - 1 - k) * dil;
        const float sc = lg[k] * inv;
        if (src >= 0) {
#pragma unroll
            for (int z = 0; z < 8; ++z) acc[z] = fmaf(sc, bf2f(vr[k][z]), acc[z]);
        } else {
            const float* bvp = bv + hko + k * HW + (j << 3);
#pragma unroll
            for (int z = 0; z < 8; ++z) acc[z] = fmaf(sc, bvp[z], acc[z]);
        }
    }

    ushort8v o;
#pragma unroll
    for (int z = 0; z < 8; ++z) o[z] = f2bf(acc[z] * 0.125f);
    const int row = b * LL + l;
    const int k8 = h * 8 + j;
    const int sw = ((k8 & 3) ^ ((l >> 1) & 3)) << 3;
    *(ushort8v*)(attnb + (size_t)row * DM + ((k8 >> 2) << 5) + sw) = o;
}

// ===========================================================================
// ------------------- round-1 fp32 fallback (small ws) ----------------------
// ===========================================================================
__global__ __launch_bounds__(256, 2) void gemm_nt_bias(
    const float* __restrict__ A, const float* __restrict__ Bm,
    const float* __restrict__ bias, float* __restrict__ C,
    int M, int N, int Kd)
{
    __shared__ float As[16][68];
    __shared__ float Bs[16][68];
    const int tid = threadIdx.x;
    const int tx = tid & 15, ty = tid >> 4;
    const int r0 = blockIdx.y << 6, c0 = blockIdx.x << 6;
    const int lr = tid >> 2, k4 = (tid & 3) << 2;
    const float* Ap = A  + (size_t)(r0 + lr) * Kd + k4;
    const float* Bp = Bm + (size_t)(c0 + lr) * Kd + k4;
    float acc[4][4];
#pragma unroll
    for (int i = 0; i < 4; ++i)
#pragma unroll
        for (int j = 0; j < 4; ++j) acc[i][j] = 0.f;
    for (int d0 = 0; d0 < Kd; d0 += 16) {
        float4 av = *(const float4*)(Ap + d0);
        float4 bv = *(const float4*)(Bp + d0);
        As[k4 + 0][lr] = av.x; As[k4 + 1][lr] = av.y;
        As[k4 + 2][lr] = av.z; As[k4 + 3][lr] = av.w;
        Bs[k4 + 0][lr] = bv.x; Bs[k4 + 1][lr] = bv.y;
        Bs[k4 + 2][lr] = bv.z; Bs[k4 + 3][lr] = bv.w;
        __syncthreads();
#pragma unroll
        for (int dd = 0; dd < 16; ++dd) {
            float4 a4 = *(const float4*)&As[dd][ty << 2];
            float4 b4 = *(const float4*)&Bs[dd][tx << 2];
            float ar[4] = {a4.x, a4.y, a4.z, a4.w};
            float br[4] = {b4.x, b4.y, b4.z, b4.w};
#pragma unroll
            for (int i = 0; i < 4; ++i)
#pragma unroll
                for (int j = 0; j < 4; ++j)
                    acc[i][j] = fmaf(ar[i], br[j], acc[i][j]);
        }
        __syncthreads();
    }
#pragma unroll
    for (int i = 0; i < 4; ++i) {
        float4 o;
        const int c = c0 + (tx << 2);
        o.x = acc[i][0] + bias[c + 0];
        o.y = acc[i][1] + bias[c + 1];
        o.z = acc[i][2] + bias[c + 2];
        o.w = acc[i][3] + bias[c + 3];
        *(float4*)&C[(size_t)(r0 + (ty << 2) + i) * N + c] = o;
    }
}

__device__ __forceinline__ void tile_gemm_f32(
    const float* __restrict__ xb, int src, bool ok,
    const float* __restrict__ wrow,
    int lr, int k4, int tx, int ty,
    float (&As)[16][68], float (&Ws)[16][68], float (&acc)[4][4])
{
#pragma unroll
    for (int i = 0; i < 4; ++i)
#pragma unroll
        for (int j = 0; j < 4; ++j) acc[i][j] = 0.f;
    const float* xrow = xb + (size_t)(ok ? src : 0) * DM + k4;
    for (int d0 = 0; d0 < DM; d0 += 16) {
        float4 av = make_float4(0.f, 0.f, 0.f, 0.f);
        if (ok) av = *(const float4*)(xrow + d0);
        float4 wv = *(const float4*)(wrow + d0);
        As[k4 + 0][lr] = av.x; As[k4 + 1][lr] = av.y;
        As[k4 + 2][lr] = av.z; As[k4 + 3][lr] = av.w;
        Ws[k4 + 0][lr] = wv.x; Ws[k4 + 1][lr] = wv.y;
        Ws[k4 + 2][lr] = wv.z; Ws[k4 + 3][lr] = wv.w;
        __syncthreads();
#pragma unroll
        for (int dd = 0; dd < 16; ++dd) {
            float4 a4 = *(const float4*)&As[dd][ty << 2];
            float4 b4 = *(const float4*)&Ws[dd][tx << 2];
            float ar[4] = {a4.x, a4.y, a4.z, a4.w};
            float br[4] = {b4.x, b4.y, b4.z, b4.w};
#pragma unroll
            for (int i = 0; i < 4; ++i)
#pragma unroll
                for (int j = 0; j < 4; ++j)
                    acc[i][j] = fmaf(ar[i], br[j], acc[i][j]);
        }
        __syncthreads();
    }
}

__global__ __launch_bounds__(256, 2) void attn_kernel(
    const float* __restrict__ x, const float* __restrict__ q,
    const float* __restrict__ Wk, const float* __restrict__ bk,
    const float* __restrict__ Wv, const float* __restrict__ bv,
    float* __restrict__ attn)
{
    __shared__ float As[16][68];
    __shared__ float Ws[16][68];
    __shared__ float qs[64][68];
    __shared__ float lg[64][17];
    __shared__ float red[64][17];
    const int tid = threadIdx.x;
    const int tx = tid & 15, ty = tid >> 4;
    const int bid = blockIdx.x;
    const int h = bid & 7, t = (bid >> 3) & 15, b = bid >> 7;
    const int l0 = t << 6;
    const int dil = c_dil[h];
    const int lr = tid >> 2, k4 = (tid & 3) << 2;
    for (int i = tid; i < 64 * 16; i += 256) {
        int l = i >> 4, o4 = (i & 15) << 2;
        float4 v = *(const float4*)&q[((size_t)(b * LL + l0 + l) * HH + h) * HW + o4];
        *(float4*)&qs[l][o4] = v;
    }
    const float* xb  = x  + (size_t)b * LL * DM;
    const float* Wkh = Wk + (size_t)h * KT * HW * DM;
    const float* Wvh = Wv + (size_t)h * KT * HW * DM;
    const float* bkh = bk + h * KT * HW;
    const float* bvh = bv + h * KT * HW;
    float acc[4][4];
    for (int kk = 0; kk < KT; ++kk) {
        const int src = l0 + lr - (KT - 1 - kk) * dil;
        const bool ok = (src >= 0) && (src < LL);
        tile_gemm_f32(xb, src, ok, Wkh + (size_t)(kk * HW + lr) * DM + k4,
                      lr, k4, tx, ty, As, Ws, acc);
        const float* bkp = bkh + kk * HW + (tx << 2);
#pragma unroll
        for (int i = 0; i < 4; ++i) {
            float p = 0.f;
#pragma unroll
            for (int j = 0; j < 4; ++j)
                p += (acc[i][j] + bkp[j]) * qs[(ty << 2) + i][(tx << 2) + j];
            red[(ty << 2) + i][tx] = p;
        }
        __syncthreads();
        if (tid < 64) {
            float s = 0.f;
#pragma unroll
            for (int u = 0; u < 16; ++u) s += red[tid][u];
            lg[tid][kk] = s;
        }
        __syncthreads();
    }
    if (tid < 64) {
        float m = lg[tid][0];
#pragma unroll
        for (int u = 1; u < KT; ++u) m = fmaxf(m, lg[tid][u]);
        float s = 0.f;
#pragma unroll
        for (int u = 0; u < KT; ++u) {
            float e = expf(lg[tid][u] - m);
            lg[tid][u] = e; s += e;
        }
        float inv = 1.f / s;
#pragma unroll
        for (int u = 0; u < KT; ++u) lg[tid][u] *= inv;
    }
    __syncthreads();
    float vacc[4][4];
#pragma unroll
    for (int i = 0; i < 4; ++i)
#pragma unroll
        for (int j = 0; j < 4; ++j) vacc[i][j] = 0.f;
    for (int kk = 0; kk < KT; ++kk) {
        const int src = l0 + lr - (KT - 1 - kk) * dil;
        const bool ok = (src >= 0) && (src < LL);
        tile_gemm_f32(xb, src, ok, Wvh + (size_t)(kk * HW + lr) * DM + k4,
                      lr, k4, tx, ty, As, Ws, acc);
        const float* bvp = bvh + kk * HW + (tx << 2);
#pragma unroll
        for (int i = 0; i < 4; ++i) {
            float sc = lg[(ty << 2) + i][kk];
#pragma unroll
            for (int j = 0; j < 4; ++j)
                vacc[i][j] = fmaf(sc, acc[i][j] + bvp[j], vacc[i][j]);
        }
    }
#pragma unroll
    for (int i = 0; i < 4; ++i) {
        float4 o;
        o.x = vacc[i][0] * 0.125f;
        o.y = vacc[i][1] * 0.125f;
        o.z = vacc[i][2] * 0.125f;
        o.w = vacc[i][3] * 0.125f;
        *(float4*)&attn[((size_t)(b * LL + l0 + (ty << 2) + i) * HH + h) * HW + (tx << 2)] = o;
    }
}

// ===========================================================================
extern "C" void kernel_launch(void* const* d_in, const int* in_sizes, int n_in,
                              void* d_out, int out_size, void* d_ws, size_t ws_size,
                              hipStream_t stream)
{
    const float* x  = (const float*)d_in[0];
    const float* Wq = (const float*)d_in[1];
    const float* bq = (const float*)d_in[2];
    const float* Wk = (const float*)d_in[3];
    const float* bk = (const float*)d_in[4];
    const float* Wv = (const float*)d_in[5];
    const float* bv = (const float*)d_in[6];
    const float* Wo = (const float*)d_in[7];
    const float* bo = (const float*)d_in[8];
    float* out = (float*)d_out;

    const int M = BD * LL;  // 2048

    // ws layout (ushort elements) for the fast path
    const size_t N_X   = (size_t)BD * LL * DM;            //  1,048,576
    const size_t N_WB  = (size_t)NQKV * DM;               //  8,650,752
    const size_t N_WO  = (size_t)DM * DM;                 //    262,144
    const size_t N_QKV = (size_t)M * NQKV;                // 34,603,008 = qb+kvb
    const size_t NEED  = (N_X + N_WB + N_WO + N_QKV + N_X) * 2;

    if (ws_size >= NEED) {
        u16* xb    = (u16*)d_ws;
        u16* wb    = xb    + N_X;      // [Wq|Wk|Wv] swizzled, 16896 x 512
        u16* wob   = wb    + N_WB;
        u16* qb    = wob   + N_WO;     // q: 2048 x 512
        u16* kvb   = qb    + N_X;      // k/v panels: 512 x 65536
        u16* attnb = qb    + N_QKV;

        cvt_swz<<<4864, 256, 0, stream>>>(x, Wq, Wk, Wv, Wo, xb, wb, wob);

        // q/k/v projections (64x128/wave, counted-vmcnt 3-buf, XCD remap)
        gemm_bf16<<<dim3(1056), 256, 0, stream>>>(
            xb, wb, bq, bk, bv, qb, kvb);

        // two-phase register-resident gather -> attnb (swizzled)
        attn_bf16<<<BD * HH * (LL / 32), 256, 0, stream>>>(
            qb, kvb, bk, bv, attnb);

        // out = attnb * Wo^T + bo -> fp32
        gemm_out<<<dim3(8, 32), 256, 0, stream>>>(attnb, wob, bo, out);
    } else {
        // fp32 fallback (round-1 path, 8 MB ws)
        float* qws = (float*)d_ws;
        float* aws = qws + (size_t)BD * LL * HH * HW;
        gemm_nt_bias<<<dim3((HH * HW) / 64, M / 64), 256, 0, stream>>>(
            x, Wq, bq, qws, M, HH * HW, DM);
        attn_kernel<<<BD * HH * (LL / 64), 256, 0, stream>>>(
            x, qws, Wk, bk, Wv, bv, aws);
        gemm_nt_bias<<<dim3(DM / 64, M / 64), 256, 0, stream>>>(
            aws, Wo, bo, out, M, DM, HH * HW);
    }
}

// Round 8
// 164.878 us; speedup vs baseline: 1.0344x; 1.0344x over previous
//
#include <hip/hip_runtime.h>

// LCSA: dilated local-window self-attention.
// B=2, L=1024, D=512, H=8, HEAD_W=64, KERNEL=16, dilations {1,1,2,2,4,4,8,8},
// MODE=forward -> src(l,k) = l - (15-k)*dil, zero-padded outside [0,L).
//
// R17: revert to R15 (measured best: gemm 54.6us) + T5 s_setprio around the
//   MFMA cluster. R16's 64x128-wave-tile test REFUTED the LDS-BW theory
//   (-25% LDS traffic -> 57.9us, regression). Seven variants R10-R16 all pin
//   MfmaUtil at 23-25% with no resource saturated -> correlated wave stalls;
//   3 blk/CU counted-vmcnt (R15) is the best decorrelation found. setprio:
//   R15's CU holds 3 blocks at different pipeline phases (stage/ds_read/MFMA)
//   -> role diversity, the T5 gate; m224 measured +34-39% on phase-split
//   schedules, m190 null only on lockstep.
// gemm_bf16: 128x128, BK=32, counted-vmcnt 3-buf, XCD remap, panel epilogue.
// attn_bf16: TWO-PHASE register-resident gather, panel layout (R14).
// cvt_swz:   fp32->bf16 + per-row XOR chunk swizzle (unchanged).
// Fallback:  round-1 fp32 path (8 MB ws).

#define BD 2
#define LL 1024
#define DM 512
#define HH 8
#define KT 16
#define HW 64

#define NQKV 16896          // legacy total: 512 q + 8192 k + 8192 v

typedef unsigned short u16;
typedef unsigned int u32;
typedef __bf16 bf16x8 __attribute__((ext_vector_type(8)));
typedef float f32x4 __attribute__((ext_vector_type(4)));
typedef unsigned short ushort4v __attribute__((ext_vector_type(4)));
typedef unsigned short ushort8v __attribute__((ext_vector_type(8)));

__constant__ int c_dil[8] = {1, 1, 2, 2, 4, 4, 8, 8};

__device__ __forceinline__ float bf2f(u16 u) {
    return __builtin_bit_cast(float, (u32)u << 16);
}
__device__ __forceinline__ u16 f2bf(float f) {   // round-to-nearest-even
    u32 u = __builtin_bit_cast(u32, f);
    return (u16)((u + 0x7fffu + ((u >> 16) & 1u)) >> 16);
}

// async global->LDS, 16 B per lane; lds dest must be (uniform base + lane*16)
__device__ __forceinline__ void gl_lds16(const u16* g, u16* l) {
    __builtin_amdgcn_global_load_lds(
        (__attribute__((address_space(1))) void*)g,
        (__attribute__((address_space(3))) void*)l, 16, 0, 0);
}

// raw workgroup barrier with compiler memory fences (proven in R11/R15)
__device__ __forceinline__ void bar() {
    asm volatile("" ::: "memory");
    __builtin_amdgcn_s_barrier();
    asm volatile("" ::: "memory");
}

// ===========================================================================
// Fused qkv projection GEMM, counted-vmcnt 3-buffer pipeline, XCD-chunked.
// A(2048x512) * [Wq|Wk|Wv]^T + bias -> qb (2048x512) and kvb panels.
// kvb panel p = ((reg*8 + h)*16 + kslot)*2 + b, 65536 u16 each (1024x64).
// 128x128 tile, BK=32, 4 waves (64x64 each), 16x16x32 MFMA, swizzled A/B,
// LDS 48KB (3 bufs) -> 3 blocks/CU. Grid 2112 linear.
//
// Block remap: wg = (bid&7)*264 + (bid>>3) (bijective, 2112 = 8*264),
//   m0 = (wg&15)*128 (fastest within XCD), n0 = (wg>>4)*128.
//
// Pipeline: prologue stages tiles 0,1; vmcnt(4) -> tile0 landed; barrier.
//   iter t: STAGE(t+2 -> buf[(t+2)%3]) (t<14); ds_read buf[t%3];
//   setprio(1); 16 MFMA; setprio(0);
//   vmcnt(4) (t<=13) or vmcnt(0) (t==14); barrier.
// ===========================================================================
__global__ __launch_bounds__(256, 3) void gemm_bf16(
    const u16* __restrict__ A, const u16* __restrict__ Bm,
    const float* __restrict__ bq, const float* __restrict__ bk,
    const float* __restrict__ bv,
    u16* __restrict__ qb, u16* __restrict__ kvb)
{
    // XCD-chunked bijective remap (8 XCDs, 2112 = 8*264 blocks)
    const int bid = blockIdx.x;
    const int wg  = (bid & 7) * 264 + (bid >> 3);
    const int m0  = (wg & 15) << 7;     // m fastest within an XCD
    const int n0  = (wg >> 4) << 7;     // 132 n-tiles of 128

    __shared__ u16 As[3][128 * 32];     // 3 x 8 KB
    __shared__ u16 Bs[3][128 * 32];     // 3 x 8 KB

    const int tid  = threadIdx.x;
    const int wave = tid >> 6, lane = tid & 63;
    const int r0 = tid >> 2;            // staging row 0..63 (round 0)
    const int cc = (tid & 3) << 3;      // staging k-offset (elements)
    const int mw = (wave >> 1) << 6;
    const int nw = (wave & 1) << 6;
    const int lr = lane & 15;
    const int qg = lane >> 4;
    const int ksw = ((qg ^ ((lr >> 1) & 3)) << 3);   // swizzled chunk

    const u16* Ag = A  + (size_t)(m0 + r0) * DM + cc;
    const u16* Bg = Bm + (size_t)(n0 + r0) * DM + cc;
    u16* lA = &As[0][0] + tid * 8;
    u16* lB = &Bs[0][0] + tid * 8;

    // stage k-tile t2 (32 wide) into buffer c (4 loads/thread)
#define STG(t2, c) do {                                                    \
        const int ko_ = (t2) << 5;                                         \
        gl_lds16(Ag + ko_,                  lA + (c) * 4096);              \
        gl_lds16(Ag + ko_ + (size_t)64*DM,  lA + (c) * 4096 + 2048);       \
        gl_lds16(Bg + ko_,                  lB + (c) * 4096);              \
        gl_lds16(Bg + ko_ + (size_t)64*DM,  lB + (c) * 4096 + 2048);       \
    } while (0)

    f32x4 acc[4][4];
#pragma unroll
    for (int i = 0; i < 4; ++i)
#pragma unroll
        for (int j = 0; j < 4; ++j) acc[i][j] = (f32x4){0.f, 0.f, 0.f, 0.f};

    STG(0, 0);
    STG(1, 1);
    asm volatile("s_waitcnt vmcnt(4)" ::: "memory");   // tile 0 landed
    bar();

#pragma unroll
    for (int t = 0; t < 16; ++t) {
        const int cur = t % 3;                         // unrolled -> literal
        if (t < 14) STG(t + 2, (t + 2) % 3);           // 2-deep prefetch

        bf16x8 af[4], bfr[4];
#pragma unroll
        for (int i = 0; i < 4; ++i)
            af[i] = *(const bf16x8*)&As[cur][(mw + (i << 4) + lr) * 32 + ksw];
#pragma unroll
        for (int j = 0; j < 4; ++j)
            bfr[j] = *(const bf16x8*)&Bs[cur][(nw + (j << 4) + lr) * 32 + ksw];
        __builtin_amdgcn_s_setprio(1);
#pragma unroll
        for (int i = 0; i < 4; ++i)
#pragma unroll
            for (int j = 0; j < 4; ++j)
                acc[i][j] = __builtin_amdgcn_mfma_f32_16x16x32_bf16(
                    af[i], bfr[j], acc[i][j], 0, 0, 0);
        __builtin_amdgcn_s_setprio(0);

        // counted wait: tile t+1 resident, t+2's loads stay in flight
        if (t < 14)
            asm volatile("s_waitcnt vmcnt(4)" ::: "memory");
        else if (t == 14)
            asm volatile("s_waitcnt vmcnt(0)" ::: "memory");
        if (t < 15) bar();
    }
#undef STG

    if (n0 < 512) {
        // ---- q region: qb[row][512] ----
#pragma unroll
        for (int i = 0; i < 4; ++i) {
            const int rowb = m0 + mw + (i << 4) + (qg << 2);
#pragma unroll
            for (int j = 0; j < 4; ++j) {
                const int col = n0 + nw + (j << 4) + lr;
                const float bs = bq[col];
#pragma unroll
                for (int r = 0; r < 4; ++r)
                    qb[(size_t)(rowb + r) * 512 + col] =
                        f2bf(acc[i][j][r] + bs);
            }
        }
    } else {
        // ---- k/v region: kvb panel ((reg*8+h)*16+kslot)*2+b, [l][64] ----
        const int reg = (n0 >= 8704);
        const float* bias = reg ? bv : bk;
        const int t0  = n0 - (reg ? 8704 : 512);   // region-local, 128-aligned
        const int h   = t0 >> 10;                  // tile within one head
        const int pb  = ((reg << 3) + h) << 4;     // (reg*8+h)*16
#pragma unroll
        for (int i = 0; i < 4; ++i) {
            const int rowb = m0 + mw + (i << 4) + (qg << 2);
#pragma unroll
            for (int j = 0; j < 4; ++j) {
                const int tcol  = (t0 & 1023) + nw + (j << 4) + lr; // head-local
                const int kslot = tcol >> 6;
                const int oo    = tcol & 63;
                const float bs  = bias[(h << 10) + tcol];
#pragma unroll
                for (int r = 0; r < 4; ++r) {
                    const int row = rowb + r;
                    const int bb  = row >> 10, l2 = row & 1023;
                    kvb[((size_t)(((pb + kslot) << 1) + bb) << 16)
                        + (l2 << 6) + oo] = f2bf(acc[i][j][r] + bs);
                }
            }
        }
    }
}

// ===========================================================================
// Output projection: out(2048x512 fp32) = attnb(2048x512 swz) * Wo^T(512x512
// swz) + bo. 64x64 tiles, grid (8,32) = 256 blocks, 4 waves (16x64 each).
// Counted-vmcnt 3-buffer pipeline (R15) + setprio.
// ===========================================================================
__global__ __launch_bounds__(256, 4) void gemm_out(
    const u16* __restrict__ A, const u16* __restrict__ Bm,
    const float* __restrict__ bias, float* __restrict__ C)
{
    __shared__ u16 As[3][64 * 32];      // 3 x 4 KB
    __shared__ u16 Bs[3][64 * 32];      // 3 x 4 KB

    const int tid  = threadIdx.x;
    const int wave = tid >> 6, lane = tid & 63;
    const int m0 = blockIdx.y << 6, n0 = blockIdx.x << 6;
    const int r0 = tid >> 2, cc = (tid & 3) << 3;
    const int mw = wave << 4;           // wave's 16-row band
    const int lr = lane & 15, qg = lane >> 4;
    const int ksw = ((qg ^ ((lr >> 1) & 3)) << 3);

    const u16* Ag = A  + (size_t)(m0 + r0) * DM + cc;
    const u16* Bg = Bm + (size_t)(n0 + r0) * DM + cc;
    u16* lA = &As[0][0] + tid * 8;
    u16* lB = &Bs[0][0] + tid * 8;

#define STG(t2, c) do {                                                    \
        const int ko_ = (t2) << 5;                                         \
        gl_lds16(Ag + ko_, lA + (c) * 2048);                               \
        gl_lds16(Bg + ko_, lB + (c) * 2048);                               \
    } while (0)

    f32x4 acc[4];
#pragma unroll
    for (int j = 0; j < 4; ++j) acc[j] = (f32x4){0.f, 0.f, 0.f, 0.f};

    STG(0, 0);
    STG(1, 1);
    asm volatile("s_waitcnt vmcnt(2)" ::: "memory");   // tile 0 landed
    bar();

#pragma unroll
    for (int t = 0; t < 16; ++t) {
        const int cur = t % 3;
        if (t < 14) STG(t + 2, (t + 2) % 3);

        bf16x8 af = *(const bf16x8*)&As[cur][(mw + lr) * 32 + ksw];
        __builtin_amdgcn_s_setprio(1);
#pragma unroll
        for (int j = 0; j < 4; ++j) {
            bf16x8 bfr = *(const bf16x8*)&Bs[cur][((j << 4) + lr) * 32 + ksw];
            acc[j] = __builtin_amdgcn_mfma_f32_16x16x32_bf16(af, bfr, acc[j], 0, 0, 0);
        }
        __builtin_amdgcn_s_setprio(0);

        if (t < 14)
            asm volatile("s_waitcnt vmcnt(2)" ::: "memory");
        else if (t == 14)
            asm volatile("s_waitcnt vmcnt(0)" ::: "memory");
        if (t < 15) bar();
    }
#undef STG

    // C row = m0+mw+4qg+r, col = n0+16j+lr
#pragma unroll
    for (int j = 0; j < 4; ++j) {
        const int col = n0 + (j << 4) + lr;
        const float bs = bias[col];
#pragma unroll
        for (int r = 0; r < 4; ++r)
            C[(size_t)(m0 + mw + (qg << 2) + r) * DM + col] = acc[j][r] + bs;
    }
}

// ===========================================================================
// fp32 -> bf16 + swizzle. One thread per 8-elem chunk: 32B read, 16B write,
// both coalesced (the XOR permutes chunks within a 64B line).
// Chunks (row*64): x 131072 | [Wq|Wk|Wv] 1081344 | Wo 32768
// Total 1245184 = 4864 blocks x 256.
// ===========================================================================
__global__ void cvt_swz(const float* __restrict__ x,  const float* __restrict__ Wq,
                        const float* __restrict__ Wk, const float* __restrict__ Wv,
                        const float* __restrict__ Wo,
                        u16* __restrict__ xb, u16* __restrict__ wb,
                        u16* __restrict__ wob)
{
    const int i = blockIdx.x * 256 + threadIdx.x;
    const float* src; u16* dst; int t;
    if (i < 131072) {
        t = i;
        src = x;  dst = xb;
    } else if (i < 1212416) {
        t = i - 131072;
        const int row = t >> 6;
        if      (row <  512) src = Wq;
        else if (row < 8704) src = Wk - (size_t)512 * DM;
        else                 src = Wv - (size_t)8704 * DM;
        dst = wb;
    } else {
        t = i - 1212416;
        src = Wo; dst = wob;
    }
    const int row = t >> 6;              // 64 chunks per row
    const int c8  = t & 63;              // output chunk within row
    const int s   = (row >> 1) & 3;
    const int oc  = (c8 & ~3) | ((c8 & 3) ^ s);   // source chunk
    const float* p = src + (size_t)row * DM + (oc << 3);
    float4 v0 = *(const float4*)p;
    float4 v1 = *(const float4*)(p + 4);
    ushort8v o = { f2bf(v0.x), f2bf(v0.y), f2bf(v0.z), f2bf(v0.w),
                   f2bf(v1.x), f2bf(v1.y), f2bf(v1.z), f2bf(v1.w) };
    *(ushort8v*)(dst + (size_t)row * DM + (c8 << 3)) = o;
}

// ===========================================================================
// attention gather, TWO-PHASE register-resident, panel layout (R14).
// 256 thr = 32 l's x 8 o-groups, grid = B*H*(L/32) = 512.
// K-load for kslot k: kvb panel ((h*16+k)*2+b) + src*64 + j*8 -> per-wave
// request = 8 lanes x 16B contiguous (128B), 8 l-groups at dil*128B stride.
// ===========================================================================
__global__ __launch_bounds__(256, 4) void attn_bf16(
    const u16* __restrict__ qb,     // (B*L, 512) bf16
    const u16* __restrict__ kvb,    // panels, see gemm_bf16
    const float* __restrict__ bk,   // (H,K,64) fp32
    const float* __restrict__ bv,
    u16* __restrict__ attnb)        // (B,L,512) bf16 swizzled
{
    const int tid = threadIdx.x;
    const int j  = tid & 7;          // o-group (8 o's)
    const int ll = tid >> 3;         // 0..31
    const int bid = blockIdx.x;
    const int h = bid & 7;
    const int t = (bid >> 3) & 31;
    const int b = bid >> 8;
    const int l = (t << 5) + ll;
    const int dil = c_dil[h];

    const int hko = h * (KT * HW);   // bias head offset

    float qf[8];
    {
        ushort8v qv = *(const ushort8v*)(qb + (size_t)(b * LL + l) * 512
                                         + h * HW + (j << 3));
#pragma unroll
        for (int z = 0; z < 8; ++z) qf[z] = bf2f(qv[z]);
    }

    // panel bases: K panel p = (h*16+k)*2+b, V panel p = ((8+h)*16+k)*2+b
    const u16* kbase = kvb + ((size_t)(((h << 4) << 1) + b) << 16) + (j << 3);
    const u16* vbase = kbase + ((size_t)(8 << 4) << 17);   // +8*16 panels *2*65536

    // ---- phase 1: all k loads in flight, then logits ----
    ushort8v kr[KT];
#pragma unroll
    for (int k = 0; k < KT; ++k) {
        const int src = l - (KT - 1 - k) * dil;
        if (src >= 0)
            kr[k] = *(const ushort8v*)(kbase + ((size_t)k << 17) + (src << 6));
    }

    float lg[KT];
#pragma unroll
    for (int k = 0; k < KT; ++k) {
        const int src = l - (KT - 1 - k) * dil;
        float p = 0.f;
        if (src >= 0) {
#pragma unroll
            for (int z = 0; z < 8; ++z) p += qf[z] * bf2f(kr[k][z]);
        } else {
            const float* bkp = bk + hko + k * HW + (j << 3);
#pragma unroll
            for (int z = 0; z < 8; ++z) p += qf[z] * bkp[z];
        }
        p += __shfl_xor(p, 1);
        p += __shfl_xor(p, 2);
        p += __shfl_xor(p, 4);
        lg[k] = p;
    }

    // ---- softmax in registers ----
    float m = lg[0];
#pragma unroll
    for (int k = 1; k < KT; ++k) m = fmaxf(m, lg[k]);
    float s = 0.f;
#pragma unroll
    for (int k = 0; k < KT; ++k) { lg[k] = __expf(lg[k] - m); s += lg[k]; }
    const float inv = 1.f / s;

    // ---- phase 2: all v loads in flight, weighted accumulate ----
    ushort8v vr[KT];
#pragma unroll
    for (int k = 0; k < KT; ++k) {
        const int src = l - (KT - 1 - k) * dil;
        if (src >= 0)
            vr[k] = *(const ushort8v*)(vbase + ((size_t)k << 17) + (src << 6));
    }

    float acc[8];
#pragma unroll
    for (int z = 0; z < 8; ++z) acc[z] = 0.f;
#pragma unroll
    for (int k = 0; k < KT; ++k) {
        const int src = l - (KT - 1 - k) * dil;
        const float sc = lg[k] * inv;
        if (src >= 0) {
#pragma unroll
            for (int z = 0; z < 8; ++z) acc[z] = fmaf(sc, bf2f(vr[k][z]), acc[z]);
        } else {
            const float* bvp = bv + hko + k * HW + (j << 3);
#pragma unroll
            for (int z = 0; z < 8; ++z) acc[z] = fmaf(sc, bvp[z], acc[z]);
        }
    }

    ushort8v o;
#pragma unroll
    for (int z = 0; z < 8; ++z) o[z] = f2bf(acc[z] * 0.125f);
    const int row = b * LL + l;
    const int k8 = h * 8 + j;
    const int sw = ((k8 & 3) ^ ((l >> 1) & 3)) << 3;
    *(ushort8v*)(attnb + (size_t)row * DM + ((k8 >> 2) << 5) + sw) = o;
}

// ===========================================================================
// ------------------- round-1 fp32 fallback (small ws) ----------------------
// ===========================================================================
__global__ __launch_bounds__(256, 2) void gemm_nt_bias(
    const float* __restrict__ A, const float* __restrict__ Bm,
    const float* __restrict__ bias, float* __restrict__ C,
    int M, int N, int Kd)
{
    __shared__ float As[16][68];
    __shared__ float Bs[16][68];
    const int tid = threadIdx.x;
    const int tx = tid & 15, ty = tid >> 4;
    const int r0 = blockIdx.y << 6, c0 = blockIdx.x << 6;
    const int lr = tid >> 2, k4 = (tid & 3) << 2;
    const float* Ap = A  + (size_t)(r0 + lr) * Kd + k4;
    const float* Bp = Bm + (size_t)(c0 + lr) * Kd + k4;
    float acc[4][4];
#pragma unroll
    for (int i = 0; i < 4; ++i)
#pragma unroll
        for (int j = 0; j < 4; ++j) acc[i][j] = 0.f;
    for (int d0 = 0; d0 < Kd; d0 += 16) {
        float4 av = *(const float4*)(Ap + d0);
        float4 bv = *(const float4*)(Bp + d0);
        As[k4 + 0][lr] = av.x; As[k4 + 1][lr] = av.y;
        As[k4 + 2][lr] = av.z; As[k4 + 3][lr] = av.w;
        Bs[k4 + 0][lr] = bv.x; Bs[k4 + 1][lr] = bv.y;
        Bs[k4 + 2][lr] = bv.z; Bs[k4 + 3][lr] = bv.w;
        __syncthreads();
#pragma unroll
        for (int dd = 0; dd < 16; ++dd) {
            float4 a4 = *(const float4*)&As[dd][ty << 2];
            float4 b4 = *(const float4*)&Bs[dd][tx << 2];
            float ar[4] = {a4.x, a4.y, a4.z, a4.w};
            float br[4] = {b4.x, b4.y, b4.z, b4.w};
#pragma unroll
            for (int i = 0; i < 4; ++i)
#pragma unroll
                for (int j = 0; j < 4; ++j)
                    acc[i][j] = fmaf(ar[i], br[j], acc[i][j]);
        }
        __syncthreads();
    }
#pragma unroll
    for (int i = 0; i < 4; ++i) {
        float4 o;
        const int c = c0 + (tx << 2);
        o.x = acc[i][0] + bias[c + 0];
        o.y = acc[i][1] + bias[c + 1];
        o.z = acc[i][2] + bias[c + 2];
        o.w = acc[i][3] + bias[c + 3];
        *(float4*)&C[(size_t)(r0 + (ty << 2) + i) * N + c] = o;
    }
}

__device__ __forceinline__ void tile_gemm_f32(
    const float* __restrict__ xb, int src, bool ok,
    const float* __restrict__ wrow,
    int lr, int k4, int tx, int ty,
    float (&As)[16][68], float (&Ws)[16][68], float (&acc)[4][4])
{
#pragma unroll
    for (int i = 0; i < 4; ++i)
#pragma unroll
        for (int j = 0; j < 4; ++j) acc[i][j] = 0.f;
    const float* xrow = xb + (size_t)(ok ? src : 0) * DM + k4;
    for (int d0 = 0; d0 < DM; d0 += 16) {
        float4 av = make_float4(0.f, 0.f, 0.f, 0.f);
        if (ok) av = *(const float4*)(xrow + d0);
        float4 wv = *(const float4*)(wrow + d0);
        As[k4 + 0][lr] = av.x; As[k4 + 1][lr] = av.y;
        As[k4 + 2][lr] = av.z; As[k4 + 3][lr] = av.w;
        Ws[k4 + 0][lr] = wv.x; Ws[k4 + 1][lr] = wv.y;
        Ws[k4 + 2][lr] = wv.z; Ws[k4 + 3][lr] = wv.w;
        __syncthreads();
#pragma unroll
        for (int dd = 0; dd < 16; ++dd) {
            float4 a4 = *(const float4*)&As[dd][ty << 2];
            float4 b4 = *(const float4*)&Ws[dd][tx << 2];
            float ar[4] = {a4.x, a4.y, a4.z, a4.w};
            float br[4] = {b4.x, b4.y, b4.z, b4.w};
#pragma unroll
            for (int i = 0; i < 4; ++i)
#pragma unroll
                for (int j = 0; j < 4; ++j)
                    acc[i][j] = fmaf(ar[i], br[j], acc[i][j]);
        }
        __syncthreads();
    }
}

__global__ __launch_bounds__(256, 2) void attn_kernel(
    const float* __restrict__ x, const float* __restrict__ q,
    const float* __restrict__ Wk, const float* __restrict__ bk,
    const float* __restrict__ Wv, const float* __restrict__ bv,
    float* __restrict__ attn)
{
    __shared__ float As[16][68];
    __shared__ float Ws[16][68];
    __shared__ float qs[64][68];
    __shared__ float lg[64][17];
    __shared__ float red[64][17];
    const int tid = threadIdx.x;
    const int tx = tid & 15, ty = tid >> 4;
    const int bid = blockIdx.x;
    const int h = bid & 7, t = (bid >> 3) & 15, b = bid >> 7;
    const int l0 = t << 6;
    const int dil = c_dil[h];
    const int lr = tid >> 2, k4 = (tid & 3) << 2;
    for (int i = tid; i < 64 * 16; i += 256) {
        int l = i >> 4, o4 = (i & 15) << 2;
        float4 v = *(const float4*)&q[((size_t)(b * LL + l0 + l) * HH + h) * HW + o4];
        *(float4*)&qs[l][o4] = v;
    }
    const float* xb  = x  + (size_t)b * LL * DM;
    const float* Wkh = Wk + (size_t)h * KT * HW * DM;
    const float* Wvh = Wv + (size_t)h * KT * HW * DM;
    const float* bkh = bk + h * KT * HW;
    const float* bvh = bv + h * KT * HW;
    float acc[4][4];
    for (int kk = 0; kk < KT; ++kk) {
        const int src = l0 + lr - (KT - 1 - kk) * dil;
        const bool ok = (src >= 0) && (src < LL);
        tile_gemm_f32(xb, src, ok, Wkh + (size_t)(kk * HW + lr) * DM + k4,
                      lr, k4, tx, ty, As, Ws, acc);
        const float* bkp = bkh + kk * HW + (tx << 2);
#pragma unroll
        for (int i = 0; i < 4; ++i) {
            float p = 0.f;
#pragma unroll
            for (int j = 0; j < 4; ++j)
                p += (acc[i][j] + bkp[j]) * qs[(ty << 2) + i][(tx << 2) + j];
            red[(ty << 2) + i][tx] = p;
        }
        __syncthreads();
        if (tid < 64) {
            float s = 0.f;
#pragma unroll
            for (int u = 0; u < 16; ++u) s += red[tid][u];
            lg[tid][kk] = s;
        }
        __syncthreads();
    }
    if (tid < 64) {
        float m = lg[tid][0];
#pragma unroll
        for (int u = 1; u < KT; ++u) m = fmaxf(m, lg[tid][u]);
        float s = 0.f;
#pragma unroll
        for (int u = 0; u < KT; ++u) {
            float e = expf(lg[tid][u] - m);
            lg[tid][u] = e; s += e;
        }
        float inv = 1.f / s;
#pragma unroll
        for (int u = 0; u < KT; ++u) lg[tid][u] *= inv;
    }
    __syncthreads();
    float vacc[4][4];
#pragma unroll
    for (int i = 0; i < 4; ++i)
#pragma unroll
        for (int j = 0; j < 4; ++j) vacc[i][j] = 0.f;
    for (int kk = 0; kk < KT; ++kk) {
        const int src = l0 + lr - (KT - 1 - kk) * dil;
        const bool ok = (src >= 0) && (src < LL);
        tile_gemm_f32(xb, src, ok, Wvh + (size_t)(kk * HW + lr) * DM + k4,
                      lr, k4, tx, ty, As, Ws, acc);
        const float* bvp = bvh + kk * HW + (tx << 2);
#pragma unroll
        for (int i = 0; i < 4; ++i) {
            float sc = lg[(ty << 2) + i][kk];
#pragma unroll
            for (int j = 0; j < 4; ++j)
                vacc[i][j] = fmaf(sc, acc[i][j] + bvp[j], vacc[i][j]);
        }
    }
#pragma unroll
    for (int i = 0; i < 4; ++i) {
        float4 o;
        o.x = vacc[i][0] * 0.125f;
        o.y = vacc[i][1] * 0.125f;
        o.z = vacc[i][2] * 0.125f;
        o.w = vacc[i][3] * 0.125f;
        *(float4*)&attn[((size_t)(b * LL + l0 + (ty << 2) + i) * HH + h) * HW + (tx << 2)] = o;
    }
}

// ===========================================================================
extern "C" void kernel_launch(void* const* d_in, const int* in_sizes, int n_in,
                              void* d_out, int out_size, void* d_ws, size_t ws_size,
                              hipStream_t stream)
{
    const float* x  = (const float*)d_in[0];
    const float* Wq = (const float*)d_in[1];
    const float* bq = (const float*)d_in[2];
    const float* Wk = (const float*)d_in[3];
    const float* bk = (const float*)d_in[4];
    const float* Wv = (const float*)d_in[5];
    const float* bv = (const float*)d_in[6];
    const float* Wo = (const float*)d_in[7];
    const float* bo = (const float*)d_in[8];
    float* out = (float*)d_out;

    const int M = BD * LL;  // 2048

    // ws layout (ushort elements) for the fast path
    const size_t N_X   = (size_t)BD * LL * DM;            //  1,048,576
    const size_t N_WB  = (size_t)NQKV * DM;               //  8,650,752
    const size_t N_WO  = (size_t)DM * DM;                 //    262,144
    const size_t N_QKV = (size_t)M * NQKV;                // 34,603,008 = qb+kvb
    const size_t NEED  = (N_X + N_WB + N_WO + N_QKV + N_X) * 2;

    if (ws_size >= NEED) {
        u16* xb    = (u16*)d_ws;
        u16* wb    = xb    + N_X;      // [Wq|Wk|Wv] swizzled, 16896 x 512
        u16* wob   = wb    + N_WB;
        u16* qb    = wob   + N_WO;     // q: 2048 x 512
        u16* kvb   = qb    + N_X;      // k/v panels: 512 x 65536
        u16* attnb = qb    + N_QKV;

        cvt_swz<<<4864, 256, 0, stream>>>(x, Wq, Wk, Wv, Wo, xb, wb, wob);

        // q/k/v projections (counted-vmcnt 3-buf + setprio, XCD remap)
        gemm_bf16<<<dim3(2112), 256, 0, stream>>>(
            xb, wb, bq, bk, bv, qb, kvb);

        // two-phase register-resident gather -> attnb (swizzled)
        attn_bf16<<<BD * HH * (LL / 32), 256, 0, stream>>>(
            qb, kvb, bk, bv, attnb);

        // out = attnb * Wo^T + bo -> fp32
        gemm_out<<<dim3(8, 32), 256, 0, stream>>>(attnb, wob, bo, out);
    } else {
        // fp32 fallback (round-1 path, 8 MB ws)
        float* qws = (float*)d_ws;
        float* aws = qws + (size_t)BD * LL * HH * HW;
        gemm_nt_bias<<<dim3((HH * HW) / 64, M / 64), 256, 0, stream>>>(
            x, Wq, bq, qws, M, HH * HW, DM);
        attn_kernel<<<BD * HH * (LL / 64), 256, 0, stream>>>(
            x, qws, Wk, bk, Wv, bv, aws);
        gemm_nt_bias<<<dim3(DM / 64, M / 64), 256, 0, stream>>>(
            aws, Wo, bo, out, M, DM, HH * HW);
    }
}

// Round 9
// 163.427 us; speedup vs baseline: 1.0436x; 1.0089x over previous
//
#include <hip/hip_runtime.h>

// LCSA: dilated local-window self-attention.
// B=2, L=1024, D=512, H=8, HEAD_W=64, KERNEL=16, dilations {1,1,2,2,4,4,8,8},
// MODE=forward -> src(l,k) = l - (15-k)*dil, zero-padded outside [0,L).
//
// R18: k-split attention gather (occupancy/latency attack on the invisible
//   ~111us non-gemm time). attn_bf16 was 512 blocks = 2 blk/CU = 2 waves/
//   SIMD, each wave serially exposing two 16-load latency batches. Now each
//   (l,j) has 2 threads (ks=0,1) handling 8 k-slots each: block 256 =
//   16l x 8j x 2ks, grid 1024 = 4 blk/CU, 4 waves/SIMD, half-length chains.
//   Softmax/acc combined across the ks pair via shfl_xor(8) (max before
//   exp -> no rescale), ks=0 lanes store.
// gemm_bf16: R17 (counted-vmcnt 3-buf + setprio + XCD remap) - 53.7us,
//   PARKED: 8 variants pin MfmaUtil 23-26%; 660 TF ~ short-K ceiling.
// gemm_out:  counted-vmcnt 3-buf + setprio (R17).
// cvt_swz:   fp32->bf16 + per-row XOR chunk swizzle (unchanged).
// Fallback:  round-1 fp32 path (8 MB ws).

#define BD 2
#define LL 1024
#define DM 512
#define HH 8
#define KT 16
#define HW 64

#define NQKV 16896          // legacy total: 512 q + 8192 k + 8192 v

typedef unsigned short u16;
typedef unsigned int u32;
typedef __bf16 bf16x8 __attribute__((ext_vector_type(8)));
typedef float f32x4 __attribute__((ext_vector_type(4)));
typedef unsigned short ushort4v __attribute__((ext_vector_type(4)));
typedef unsigned short ushort8v __attribute__((ext_vector_type(8)));

__constant__ int c_dil[8] = {1, 1, 2, 2, 4, 4, 8, 8};

__device__ __forceinline__ float bf2f(u16 u) {
    return __builtin_bit_cast(float, (u32)u << 16);
}
__device__ __forceinline__ u16 f2bf(float f) {   // round-to-nearest-even
    u32 u = __builtin_bit_cast(u32, f);
    return (u16)((u + 0x7fffu + ((u >> 16) & 1u)) >> 16);
}

// async global->LDS, 16 B per lane; lds dest must be (uniform base + lane*16)
__device__ __forceinline__ void gl_lds16(const u16* g, u16* l) {
    __builtin_amdgcn_global_load_lds(
        (__attribute__((address_space(1))) void*)g,
        (__attribute__((address_space(3))) void*)l, 16, 0, 0);
}

// raw workgroup barrier with compiler memory fences (proven in R11/R15)
__device__ __forceinline__ void bar() {
    asm volatile("" ::: "memory");
    __builtin_amdgcn_s_barrier();
    asm volatile("" ::: "memory");
}

// ===========================================================================
// Fused qkv projection GEMM, counted-vmcnt 3-buffer pipeline, XCD-chunked.
// A(2048x512) * [Wq|Wk|Wv]^T + bias -> qb (2048x512) and kvb panels.
// kvb panel p = ((reg*8 + h)*16 + kslot)*2 + b, 65536 u16 each (1024x64).
// 128x128 tile, BK=32, 4 waves (64x64 each), 16x16x32 MFMA, swizzled A/B,
// LDS 48KB (3 bufs) -> 3 blocks/CU. Grid 2112 linear.  [R17, parked]
// ===========================================================================
__global__ __launch_bounds__(256, 3) void gemm_bf16(
    const u16* __restrict__ A, const u16* __restrict__ Bm,
    const float* __restrict__ bq, const float* __restrict__ bk,
    const float* __restrict__ bv,
    u16* __restrict__ qb, u16* __restrict__ kvb)
{
    // XCD-chunked bijective remap (8 XCDs, 2112 = 8*264 blocks)
    const int bid = blockIdx.x;
    const int wg  = (bid & 7) * 264 + (bid >> 3);
    const int m0  = (wg & 15) << 7;     // m fastest within an XCD
    const int n0  = (wg >> 4) << 7;     // 132 n-tiles of 128

    __shared__ u16 As[3][128 * 32];     // 3 x 8 KB
    __shared__ u16 Bs[3][128 * 32];     // 3 x 8 KB

    const int tid  = threadIdx.x;
    const int wave = tid >> 6, lane = tid & 63;
    const int r0 = tid >> 2;            // staging row 0..63 (round 0)
    const int cc = (tid & 3) << 3;      // staging k-offset (elements)
    const int mw = (wave >> 1) << 6;
    const int nw = (wave & 1) << 6;
    const int lr = lane & 15;
    const int qg = lane >> 4;
    const int ksw = ((qg ^ ((lr >> 1) & 3)) << 3);   // swizzled chunk

    const u16* Ag = A  + (size_t)(m0 + r0) * DM + cc;
    const u16* Bg = Bm + (size_t)(n0 + r0) * DM + cc;
    u16* lA = &As[0][0] + tid * 8;
    u16* lB = &Bs[0][0] + tid * 8;

    // stage k-tile t2 (32 wide) into buffer c (4 loads/thread)
#define STG(t2, c) do {                                                    \
        const int ko_ = (t2) << 5;                                         \
        gl_lds16(Ag + ko_,                  lA + (c) * 4096);              \
        gl_lds16(Ag + ko_ + (size_t)64*DM,  lA + (c) * 4096 + 2048);       \
        gl_lds16(Bg + ko_,                  lB + (c) * 4096);              \
        gl_lds16(Bg + ko_ + (size_t)64*DM,  lB + (c) * 4096 + 2048);       \
    } while (0)

    f32x4 acc[4][4];
#pragma unroll
    for (int i = 0; i < 4; ++i)
#pragma unroll
        for (int j = 0; j < 4; ++j) acc[i][j] = (f32x4){0.f, 0.f, 0.f, 0.f};

    STG(0, 0);
    STG(1, 1);
    asm volatile("s_waitcnt vmcnt(4)" ::: "memory");   // tile 0 landed
    bar();

#pragma unroll
    for (int t = 0; t < 16; ++t) {
        const int cur = t % 3;                         // unrolled -> literal
        if (t < 14) STG(t + 2, (t + 2) % 3);           // 2-deep prefetch

        bf16x8 af[4], bfr[4];
#pragma unroll
        for (int i = 0; i < 4; ++i)
            af[i] = *(const bf16x8*)&As[cur][(mw + (i << 4) + lr) * 32 + ksw];
#pragma unroll
        for (int j = 0; j < 4; ++j)
            bfr[j] = *(const bf16x8*)&Bs[cur][(nw + (j << 4) + lr) * 32 + ksw];
        __builtin_amdgcn_s_setprio(1);
#pragma unroll
        for (int i = 0; i < 4; ++i)
#pragma unroll
            for (int j = 0; j < 4; ++j)
                acc[i][j] = __builtin_amdgcn_mfma_f32_16x16x32_bf16(
                    af[i], bfr[j], acc[i][j], 0, 0, 0);
        __builtin_amdgcn_s_setprio(0);

        // counted wait: tile t+1 resident, t+2's loads stay in flight
        if (t < 14)
            asm volatile("s_waitcnt vmcnt(4)" ::: "memory");
        else if (t == 14)
            asm volatile("s_waitcnt vmcnt(0)" ::: "memory");
        if (t < 15) bar();
    }
#undef STG

    if (n0 < 512) {
        // ---- q region: qb[row][512] ----
#pragma unroll
        for (int i = 0; i < 4; ++i) {
            const int rowb = m0 + mw + (i << 4) + (qg << 2);
#pragma unroll
            for (int j = 0; j < 4; ++j) {
                const int col = n0 + nw + (j << 4) + lr;
                const float bs = bq[col];
#pragma unroll
                for (int r = 0; r < 4; ++r)
                    qb[(size_t)(rowb + r) * 512 + col] =
                        f2bf(acc[i][j][r] + bs);
            }
        }
    } else {
        // ---- k/v region: kvb panel ((reg*8+h)*16+kslot)*2+b, [l][64] ----
        const int reg = (n0 >= 8704);
        const float* bias = reg ? bv : bk;
        const int t0  = n0 - (reg ? 8704 : 512);   // region-local, 128-aligned
        const int h   = t0 >> 10;                  // tile within one head
        const int pb  = ((reg << 3) + h) << 4;     // (reg*8+h)*16
#pragma unroll
        for (int i = 0; i < 4; ++i) {
            const int rowb = m0 + mw + (i << 4) + (qg << 2);
#pragma unroll
            for (int j = 0; j < 4; ++j) {
                const int tcol  = (t0 & 1023) + nw + (j << 4) + lr; // head-local
                const int kslot = tcol >> 6;
                const int oo    = tcol & 63;
                const float bs  = bias[(h << 10) + tcol];
#pragma unroll
                for (int r = 0; r < 4; ++r) {
                    const int row = rowb + r;
                    const int bb  = row >> 10, l2 = row & 1023;
                    kvb[((size_t)(((pb + kslot) << 1) + bb) << 16)
                        + (l2 << 6) + oo] = f2bf(acc[i][j][r] + bs);
                }
            }
        }
    }
}

// ===========================================================================
// Output projection: out(2048x512 fp32) = attnb(2048x512 swz) * Wo^T(512x512
// swz) + bo. 64x64 tiles, grid (8,32) = 256 blocks, 4 waves (16x64 each).
// Counted-vmcnt 3-buffer pipeline + setprio (R17).
// ===========================================================================
__global__ __launch_bounds__(256, 4) void gemm_out(
    const u16* __restrict__ A, const u16* __restrict__ Bm,
    const float* __restrict__ bias, float* __restrict__ C)
{
    __shared__ u16 As[3][64 * 32];      // 3 x 4 KB
    __shared__ u16 Bs[3][64 * 32];      // 3 x 4 KB

    const int tid  = threadIdx.x;
    const int wave = tid >> 6, lane = tid & 63;
    const int m0 = blockIdx.y << 6, n0 = blockIdx.x << 6;
    const int r0 = tid >> 2, cc = (tid & 3) << 3;
    const int mw = wave << 4;           // wave's 16-row band
    const int lr = lane & 15, qg = lane >> 4;
    const int ksw = ((qg ^ ((lr >> 1) & 3)) << 3);

    const u16* Ag = A  + (size_t)(m0 + r0) * DM + cc;
    const u16* Bg = Bm + (size_t)(n0 + r0) * DM + cc;
    u16* lA = &As[0][0] + tid * 8;
    u16* lB = &Bs[0][0] + tid * 8;

#define STG(t2, c) do {                                                    \
        const int ko_ = (t2) << 5;                                         \
        gl_lds16(Ag + ko_, lA + (c) * 2048);                               \
        gl_lds16(Bg + ko_, lB + (c) * 2048);                               \
    } while (0)

    f32x4 acc[4];
#pragma unroll
    for (int j = 0; j < 4; ++j) acc[j] = (f32x4){0.f, 0.f, 0.f, 0.f};

    STG(0, 0);
    STG(1, 1);
    asm volatile("s_waitcnt vmcnt(2)" ::: "memory");   // tile 0 landed
    bar();

#pragma unroll
    for (int t = 0; t < 16; ++t) {
        const int cur = t % 3;
        if (t < 14) STG(t + 2, (t + 2) % 3);

        bf16x8 af = *(const bf16x8*)&As[cur][(mw + lr) * 32 + ksw];
        __builtin_amdgcn_s_setprio(1);
#pragma unroll
        for (int j = 0; j < 4; ++j) {
            bf16x8 bfr = *(const bf16x8*)&Bs[cur][((j << 4) + lr) * 32 + ksw];
            acc[j] = __builtin_amdgcn_mfma_f32_16x16x32_bf16(af, bfr, acc[j], 0, 0, 0);
        }
        __builtin_amdgcn_s_setprio(0);

        if (t < 14)
            asm volatile("s_waitcnt vmcnt(2)" ::: "memory");
        else if (t == 14)
            asm volatile("s_waitcnt vmcnt(0)" ::: "memory");
        if (t < 15) bar();
    }
#undef STG

    // C row = m0+mw+4qg+r, col = n0+16j+lr
#pragma unroll
    for (int j = 0; j < 4; ++j) {
        const int col = n0 + (j << 4) + lr;
        const float bs = bias[col];
#pragma unroll
        for (int r = 0; r < 4; ++r)
            C[(size_t)(m0 + mw + (qg << 2) + r) * DM + col] = acc[j][r] + bs;
    }
}

// ===========================================================================
// fp32 -> bf16 + swizzle. One thread per 8-elem chunk: 32B read, 16B write,
// both coalesced (the XOR permutes chunks within a 64B line).
// Chunks (row*64): x 131072 | [Wq|Wk|Wv] 1081344 | Wo 32768
// Total 1245184 = 4864 blocks x 256.
// ===========================================================================
__global__ void cvt_swz(const float* __restrict__ x,  const float* __restrict__ Wq,
                        const float* __restrict__ Wk, const float* __restrict__ Wv,
                        const float* __restrict__ Wo,
                        u16* __restrict__ xb, u16* __restrict__ wb,
                        u16* __restrict__ wob)
{
    const int i = blockIdx.x * 256 + threadIdx.x;
    const float* src; u16* dst; int t;
    if (i < 131072) {
        t = i;
        src = x;  dst = xb;
    } else if (i < 1212416) {
        t = i - 131072;
        const int row = t >> 6;
        if      (row <  512) src = Wq;
        else if (row < 8704) src = Wk - (size_t)512 * DM;
        else                 src = Wv - (size_t)8704 * DM;
        dst = wb;
    } else {
        t = i - 1212416;
        src = Wo; dst = wob;
    }
    const int row = t >> 6;              // 64 chunks per row
    const int c8  = t & 63;              // output chunk within row
    const int s   = (row >> 1) & 3;
    const int oc  = (c8 & ~3) | ((c8 & 3) ^ s);   // source chunk
    const float* p = src + (size_t)row * DM + (oc << 3);
    float4 v0 = *(const float4*)p;
    float4 v1 = *(const float4*)(p + 4);
    ushort8v o = { f2bf(v0.x), f2bf(v0.y), f2bf(v0.z), f2bf(v0.w),
                   f2bf(v1.x), f2bf(v1.y), f2bf(v1.z), f2bf(v1.w) };
    *(ushort8v*)(dst + (size_t)row * DM + (c8 << 3)) = o;
}

// ===========================================================================
// attention gather, K-SPLIT two-phase register-resident, panel layout.
// 256 thr = 16 l's x 8 o-groups x 2 k-halves; grid = B*H*(L/16) = 1024
// -> 4 blk/CU, 4 waves/SIMD (2x R17's occupancy), 8-load latency chains
// (half R17's). Lane map: j = lane&7, ks = lane bit 3, l-part = lane>>4.
// Logit reduce over j via shfl_xor(1,2,4); k-half combine via shfl_xor(8):
// max combined BEFORE exp (no rescale), sum and acc pairwise-added;
// ks=0 lanes store.
// ===========================================================================
__global__ __launch_bounds__(256, 4) void attn_bf16(
    const u16* __restrict__ qb,     // (B*L, 512) bf16
    const u16* __restrict__ kvb,    // panels, see gemm_bf16
    const float* __restrict__ bk,   // (H,K,64) fp32
    const float* __restrict__ bv,
    u16* __restrict__ attnb)        // (B,L,512) bf16 swizzled
{
    const int tid = threadIdx.x;
    const int j   = tid & 7;         // o-group (8 o's)
    const int ks  = (tid >> 3) & 1;  // k-half: k = ks*8 + kk
    const int ll  = tid >> 4;        // 0..15
    const int bid = blockIdx.x;
    const int h = bid & 7;
    const int t = (bid >> 3) & 63;   // L/16 = 64 l-tiles
    const int b = bid >> 9;
    const int l = (t << 4) + ll;
    const int dil = c_dil[h];
    const int kof = ks << 3;         // 0 or 8

    const int hko = h * (KT * HW);   // bias head offset

    float qf[8];
    {
        ushort8v qv = *(const ushort8v*)(qb + (size_t)(b * LL + l) * 512
                                         + h * HW + (j << 3));
#pragma unroll
        for (int z = 0; z < 8; ++z) qf[z] = bf2f(qv[z]);
    }

    // panel bases: K panel p = (h*16+k)*2+b, V panel p = ((8+h)*16+k)*2+b
    const u16* kbase = kvb + ((size_t)(((h << 4) << 1) + b) << 16) + (j << 3);
    const u16* vbase = kbase + ((size_t)(8 << 4) << 17);   // +8*16 panels *2*65536

    // ---- phase 1: this half's 8 k loads in flight, then logits ----
    ushort8v kr[8];
#pragma unroll
    for (int kk = 0; kk < 8; ++kk) {
        const int k = kof + kk;
        const int src = l - (KT - 1 - k) * dil;
        if (src >= 0)
            kr[kk] = *(const ushort8v*)(kbase + ((size_t)k << 17) + (src << 6));
    }

    float lg[8];
#pragma unroll
    for (int kk = 0; kk < 8; ++kk) {
        const int k = kof + kk;
        const int src = l - (KT - 1 - k) * dil;
        float p = 0.f;
        if (src >= 0) {
#pragma unroll
            for (int z = 0; z < 8; ++z) p += qf[z] * bf2f(kr[kk][z]);
        } else {
            const float* bkp = bk + hko + k * HW + (j << 3);
#pragma unroll
            for (int z = 0; z < 8; ++z) p += qf[z] * bkp[z];
        }
        p += __shfl_xor(p, 1);
        p += __shfl_xor(p, 2);
        p += __shfl_xor(p, 4);
        lg[kk] = p;
    }

    // ---- softmax: local 8, then combine across k-half pair (lane bit 3) ----
    float m = lg[0];
#pragma unroll
    for (int kk = 1; kk < 8; ++kk) m = fmaxf(m, lg[kk]);
    m = fmaxf(m, __shfl_xor(m, 8));          // global max over 16 k's
    float s = 0.f;
#pragma unroll
    for (int kk = 0; kk < 8; ++kk) { lg[kk] = __expf(lg[kk] - m); s += lg[kk]; }
    s += __shfl_xor(s, 8);                   // global sum
    const float inv = 1.f / s;

    // ---- phase 2: this half's 8 v loads in flight, weighted accumulate ----
    ushort8v vr[8];
#pragma unroll
    for (int kk = 0; kk < 8; ++kk) {
        const int k = kof + kk;
        const int src = l - (KT - 1 - k) * dil;
        if (src >= 0)
            vr[kk] = *(const ushort8v*)(vbase + ((size_t)k << 17) + (src << 6));
    }

    float acc[8];
#pragma unroll
    for (int z = 0; z < 8; ++z) acc[z] = 0.f;
#pragma unroll
    for (int kk = 0; kk < 8; ++kk) {
        const int k = kof + kk;
        const int src = l - (KT - 1 - k) * dil;
        const float sc = lg[kk] * inv;
        if (src >= 0) {
#pragma unroll
            for (int z = 0; z < 8; ++z) acc[z] = fmaf(sc, bf2f(vr[kk][z]), acc[z]);
        } else {
            const float* bvp = bv + hko + k * HW + (j << 3);
#pragma unroll
            for (int z = 0; z < 8; ++z) acc[z] = fmaf(sc, bvp[z], acc[z]);
        }
    }

    // combine the two k-halves (both lanes end up with the total)
#pragma unroll
    for (int z = 0; z < 8; ++z) acc[z] += __shfl_xor(acc[z], 8);

    if (ks == 0) {
        ushort8v o;
#pragma unroll
        for (int z = 0; z < 8; ++z) o[z] = f2bf(acc[z] * 0.125f);
        const int row = b * LL + l;
        const int k8 = h * 8 + j;
        const int sw = ((k8 & 3) ^ ((l >> 1) & 3)) << 3;
        *(ushort8v*)(attnb + (size_t)row * DM + ((k8 >> 2) << 5) + sw) = o;
    }
}

// ===========================================================================
// ------------------- round-1 fp32 fallback (small ws) ----------------------
// ===========================================================================
__global__ __launch_bounds__(256, 2) void gemm_nt_bias(
    const float* __restrict__ A, const float* __restrict__ Bm,
    const float* __restrict__ bias, float* __restrict__ C,
    int M, int N, int Kd)
{
    __shared__ float As[16][68];
    __shared__ float Bs[16][68];
    const int tid = threadIdx.x;
    const int tx = tid & 15, ty = tid >> 4;
    const int r0 = blockIdx.y << 6, c0 = blockIdx.x << 6;
    const int lr = tid >> 2, k4 = (tid & 3) << 2;
    const float* Ap = A  + (size_t)(r0 + lr) * Kd + k4;
    const float* Bp = Bm + (size_t)(c0 + lr) * Kd + k4;
    float acc[4][4];
#pragma unroll
    for (int i = 0; i < 4; ++i)
#pragma unroll
        for (int j = 0; j < 4; ++j) acc[i][j] = 0.f;
    for (int d0 = 0; d0 < Kd; d0 += 16) {
        float4 av = *(const float4*)(Ap + d0);
        float4 bv = *(const float4*)(Bp + d0);
        As[k4 + 0][lr] = av.x; As[k4 + 1][lr] = av.y;
        As[k4 + 2][lr] = av.z; As[k4 + 3][lr] = av.w;
        Bs[k4 + 0][lr] = bv.x; Bs[k4 + 1][lr] = bv.y;
        Bs[k4 + 2][lr] = bv.z; Bs[k4 + 3][lr] = bv.w;
        __syncthreads();
#pragma unroll
        for (int dd = 0; dd < 16; ++dd) {
            float4 a4 = *(const float4*)&As[dd][ty << 2];
            float4 b4 = *(const float4*)&Bs[dd][tx << 2];
            float ar[4] = {a4.x, a4.y, a4.z, a4.w};
            float br[4] = {b4.x, b4.y, b4.z, b4.w};
#pragma unroll
            for (int i = 0; i < 4; ++i)
#pragma unroll
                for (int j = 0; j < 4; ++j)
                    acc[i][j] = fmaf(ar[i], br[j], acc[i][j]);
        }
        __syncthreads();
    }
#pragma unroll
    for (int i = 0; i < 4; ++i) {
        float4 o;
        const int c = c0 + (tx << 2);
        o.x = acc[i][0] + bias[c + 0];
        o.y = acc[i][1] + bias[c + 1];
        o.z = acc[i][2] + bias[c + 2];
        o.w = acc[i][3] + bias[c + 3];
        *(float4*)&C[(size_t)(r0 + (ty << 2) + i) * N + c] = o;
    }
}

__device__ __forceinline__ void tile_gemm_f32(
    const float* __restrict__ xb, int src, bool ok,
    const float* __restrict__ wrow,
    int lr, int k4, int tx, int ty,
    float (&As)[16][68], float (&Ws)[16][68], float (&acc)[4][4])
{
#pragma unroll
    for (int i = 0; i < 4; ++i)
#pragma unroll
        for (int j = 0; j < 4; ++j) acc[i][j] = 0.f;
    const float* xrow = xb + (size_t)(ok ? src : 0) * DM + k4;
    for (int d0 = 0; d0 < DM; d0 += 16) {
        float4 av = make_float4(0.f, 0.f, 0.f, 0.f);
        if (ok) av = *(const float4*)(xrow + d0);
        float4 wv = *(const float4*)(wrow + d0);
        As[k4 + 0][lr] = av.x; As[k4 + 1][lr] = av.y;
        As[k4 + 2][lr] = av.z; As[k4 + 3][lr] = av.w;
        Ws[k4 + 0][lr] = wv.x; Ws[k4 + 1][lr] = wv.y;
        Ws[k4 + 2][lr] = wv.z; Ws[k4 + 3][lr] = wv.w;
        __syncthreads();
#pragma unroll
        for (int dd = 0; dd < 16; ++dd) {
            float4 a4 = *(const float4*)&As[dd][ty << 2];
            float4 b4 = *(const float4*)&Ws[dd][tx << 2];
            float ar[4] = {a4.x, a4.y, a4.z, a4.w};
            float br[4] = {b4.x, b4.y, b4.z, b4.w};
#pragma unroll
            for (int i = 0; i < 4; ++i)
#pragma unroll
                for (int j = 0; j < 4; ++j)
                    acc[i][j] = fmaf(ar[i], br[j], acc[i][j]);
        }
        __syncthreads();
    }
}

__global__ __launch_bounds__(256, 2) void attn_kernel(
    const float* __restrict__ x, const float* __restrict__ q,
    const float* __restrict__ Wk, const float* __restrict__ bk,
    const float* __restrict__ Wv, const float* __restrict__ bv,
    float* __restrict__ attn)
{
    __shared__ float As[16][68];
    __shared__ float Ws[16][68];
    __shared__ float qs[64][68];
    __shared__ float lg[64][17];
    __shared__ float red[64][17];
    const int tid = threadIdx.x;
    const int tx = tid & 15, ty = tid >> 4;
    const int bid = blockIdx.x;
    const int h = bid & 7, t = (bid >> 3) & 15, b = bid >> 7;
    const int l0 = t << 6;
    const int dil = c_dil[h];
    const int lr = tid >> 2, k4 = (tid & 3) << 2;
    for (int i = tid; i < 64 * 16; i += 256) {
        int l = i >> 4, o4 = (i & 15) << 2;
        float4 v = *(const float4*)&q[((size_t)(b * LL + l0 + l) * HH + h) * HW + o4];
        *(float4*)&qs[l][o4] = v;
    }
    const float* xb  = x  + (size_t)b * LL * DM;
    const float* Wkh = Wk + (size_t)h * KT * HW * DM;
    const float* Wvh = Wv + (size_t)h * KT * HW * DM;
    const float* bkh = bk + h * KT * HW;
    const float* bvh = bv + h * KT * HW;
    float acc[4][4];
    for (int kk = 0; kk < KT; ++kk) {
        const int src = l0 + lr - (KT - 1 - kk) * dil;
        const bool ok = (src >= 0) && (src < LL);
        tile_gemm_f32(xb, src, ok, Wkh + (size_t)(kk * HW + lr) * DM + k4,
                      lr, k4, tx, ty, As, Ws, acc);
        const float* bkp = bkh + kk * HW + (tx << 2);
#pragma unroll
        for (int i = 0; i < 4; ++i) {
            float p = 0.f;
#pragma unroll
            for (int j = 0; j < 4; ++j)
                p += (acc[i][j] + bkp[j]) * qs[(ty << 2) + i][(tx << 2) + j];
            red[(ty << 2) + i][tx] = p;
        }
        __syncthreads();
        if (tid < 64) {
            float s = 0.f;
#pragma unroll
            for (int u = 0; u < 16; ++u) s += red[tid][u];
            lg[tid][kk] = s;
        }
        __syncthreads();
    }
    if (tid < 64) {
        float m = lg[tid][0];
#pragma unroll
        for (int u = 1; u < KT; ++u) m = fmaxf(m, lg[tid][u]);
        float s = 0.f;
#pragma unroll
        for (int u = 0; u < KT; ++u) {
            float e = expf(lg[tid][u] - m);
            lg[tid][u] = e; s += e;
        }
        float inv = 1.f / s;
#pragma unroll
        for (int u = 0; u < KT; ++u) lg[tid][u] *= inv;
    }
    __syncthreads();
    float vacc[4][4];
#pragma unroll
    for (int i = 0; i < 4; ++i)
#pragma unroll
        for (int j = 0; j < 4; ++j) vacc[i][j] = 0.f;
    for (int kk = 0; kk < KT; ++kk) {
        const int src = l0 + lr - (KT - 1 - kk) * dil;
        const bool ok = (src >= 0) && (src < LL);
        tile_gemm_f32(xb, src, ok, Wvh + (size_t)(kk * HW + lr) * DM + k4,
                      lr, k4, tx, ty, As, Ws, acc);
        const float* bvp = bvh + kk * HW + (tx << 2);
#pragma unroll
        for (int i = 0; i < 4; ++i) {
            float sc = lg[(ty << 2) + i][kk];
#pragma unroll
            for (int j = 0; j < 4; ++j)
                vacc[i][j] = fmaf(sc, acc[i][j] + bvp[j], vacc[i][j]);
        }
    }
#pragma unroll
    for (int i = 0; i < 4; ++i) {
        float4 o;
        o.x = vacc[i][0] * 0.125f;
        o.y = vacc[i][1] * 0.125f;
        o.z = vacc[i][2] * 0.125f;
        o.w = vacc[i][3] * 0.125f;
        *(float4*)&attn[((size_t)(b * LL + l0 + (ty << 2) + i) * HH + h) * HW + (tx << 2)] = o;
    }
}

// ===========================================================================
extern "C" void kernel_launch(void* const* d_in, const int* in_sizes, int n_in,
                              void* d_out, int out_size, void* d_ws, size_t ws_size,
                              hipStream_t stream)
{
    const float* x  = (const float*)d_in[0];
    const float* Wq = (const float*)d_in[1];
    const float* bq = (const float*)d_in[2];
    const float* Wk = (const float*)d_in[3];
    const float* bk = (const float*)d_in[4];
    const float* Wv = (const float*)d_in[5];
    const float* bv = (const float*)d_in[6];
    const float* Wo = (const float*)d_in[7];
    const float* bo = (const float*)d_in[8];
    float* out = (float*)d_out;

    const int M = BD * LL;  // 2048

    // ws layout (ushort elements) for the fast path
    const size_t N_X   = (size_t)BD * LL * DM;            //  1,048,576
    const size_t N_WB  = (size_t)NQKV * DM;               //  8,650,752
    const size_t N_WO  = (size_t)DM * DM;                 //    262,144
    const size_t N_QKV = (size_t)M * NQKV;                // 34,603,008 = qb+kvb
    const size_t NEED  = (N_X + N_WB + N_WO + N_QKV + N_X) * 2;

    if (ws_size >= NEED) {
        u16* xb    = (u16*)d_ws;
        u16* wb    = xb    + N_X;      // [Wq|Wk|Wv] swizzled, 16896 x 512
        u16* wob   = wb    + N_WB;
        u16* qb    = wob   + N_WO;     // q: 2048 x 512
        u16* kvb   = qb    + N_X;      // k/v panels: 512 x 65536
        u16* attnb = qb    + N_QKV;

        cvt_swz<<<4864, 256, 0, stream>>>(x, Wq, Wk, Wv, Wo, xb, wb, wob);

        // q/k/v projections (counted-vmcnt 3-buf + setprio, XCD remap)
        gemm_bf16<<<dim3(2112), 256, 0, stream>>>(
            xb, wb, bq, bk, bv, qb, kvb);

        // k-split two-phase gather -> attnb (swizzled); grid B*H*(L/16)
        attn_bf16<<<BD * HH * (LL / 16), 256, 0, stream>>>(
            qb, kvb, bk, bv, attnb);

        // out = attnb * Wo^T + bo -> fp32
        gemm_out<<<dim3(8, 32), 256, 0, stream>>>(attnb, wob, bo, out);
    } else {
        // fp32 fallback (round-1 path, 8 MB ws)
        float* qws = (float*)d_ws;
        float* aws = qws + (size_t)BD * LL * HH * HW;
        gemm_nt_bias<<<dim3((HH * HW) / 64, M / 64), 256, 0, stream>>>(
            x, Wq, bq, qws, M, HH * HW, DM);
        attn_kernel<<<BD * HH * (LL / 64), 256, 0, stream>>>(
            x, qws, Wk, bk, Wv, bv, aws);
        gemm_nt_bias<<<dim3(DM / 64, M / 64), 256, 0, stream>>>(
            aws, Wo, bo, out, M, DM, HH * HW);
    }
}

// Round 10
// 161.579 us; speedup vs baseline: 1.0555x; 1.0114x over previous
//
#include <hip/hip_runtime.h>

// LCSA: dilated local-window self-attention.
// B=2, L=1024, D=512, H=8, HEAD_W=64, KERNEL=16, dilations {1,1,2,2,4,4,8,8},
// MODE=forward -> src(l,k) = l - (15-k)*dil, zero-padded outside [0,L).
//
// R19: L2-staging-bandwidth test on gemm_bf16. R15's counters imply staging
//   pulls ~50 B/cyc/CU through L2 vs ~56 ceiling (89%) -- the one near-
//   saturated resource, invariant across R10-R17. R16 cut it 25% but was
//   confounded (2 blk/CU + VGPR pressure). Clean test: 128x256 tile with
//   512 thr / 8 waves (wave tile stays 64x64, acc 64 VGPR), BK=32, 3-buf
//   counted-vmcnt (72KB -> 2 blk/CU = 16 waves/CU > R15's 12), 3 loads/
//   stage -> vmcnt(3). Staged bytes/FLOP -25% at HIGHER wave count.
//   Null read (52-56us): L2-BW refuted -> structural floor, declare plateau.
// attn_bf16: k-split two-phase gather (R18).
// gemm_out:  counted-vmcnt 3-buf + setprio (R17).
// cvt_swz:   fp32->bf16 + per-row XOR chunk swizzle (unchanged).
// Fallback:  round-1 fp32 path (8 MB ws).

#define BD 2
#define LL 1024
#define DM 512
#define HH 8
#define KT 16
#define HW 64

#define NQKV 16896          // legacy total: 512 q + 8192 k + 8192 v

typedef unsigned short u16;
typedef unsigned int u32;
typedef __bf16 bf16x8 __attribute__((ext_vector_type(8)));
typedef float f32x4 __attribute__((ext_vector_type(4)));
typedef unsigned short ushort4v __attribute__((ext_vector_type(4)));
typedef unsigned short ushort8v __attribute__((ext_vector_type(8)));

__constant__ int c_dil[8] = {1, 1, 2, 2, 4, 4, 8, 8};

__device__ __forceinline__ float bf2f(u16 u) {
    return __builtin_bit_cast(float, (u32)u << 16);
}
__device__ __forceinline__ u16 f2bf(float f) {   // round-to-nearest-even
    u32 u = __builtin_bit_cast(u32, f);
    return (u16)((u + 0x7fffu + ((u >> 16) & 1u)) >> 16);
}

// async global->LDS, 16 B per lane; lds dest must be (uniform base + lane*16)
__device__ __forceinline__ void gl_lds16(const u16* g, u16* l) {
    __builtin_amdgcn_global_load_lds(
        (__attribute__((address_space(1))) void*)g,
        (__attribute__((address_space(3))) void*)l, 16, 0, 0);
}

// raw workgroup barrier with compiler memory fences (proven in R11/R15)
__device__ __forceinline__ void bar() {
    asm volatile("" ::: "memory");
    __builtin_amdgcn_s_barrier();
    asm volatile("" ::: "memory");
}

// ===========================================================================
// Fused qkv projection GEMM: 128x256 tile, 8 waves (64x64 each), BK=32,
// counted-vmcnt 3-buffer pipeline, XCD-chunked. 512 threads.
// A(2048x512) * [Wq|Wk|Wv]^T + bias -> qb (2048x512) and kvb panels.
// kvb panel p = ((reg*8 + h)*16 + kslot)*2 + b, 65536 u16 each (1024x64).
// LDS 72KB (3 bufs x (A 8KB + B 16KB)) -> 2 blocks/CU = 16 waves/CU.
// Staged bytes per FLOP -25% vs R15 at HIGHER resident-wave count.
//
// Block remap: wg = (bid&7)*132 + (bid>>3) (bijective, 1056 = 8*132),
//   m0 = (wg&15)*128 (fastest within XCD), n0 = (wg>>4)*256 (66 n-tiles;
//   region boundaries 512 and 8704 are 256-aligned -> no tile straddle).
//
// Pipeline (3 gl_lds16 per stage): prologue stages tiles 0,1; vmcnt(3);
//   iter t: STG(t+2 -> buf[(t+2)%3]) (t<14); ds_read buf[t%3];
//   setprio(1); 16 MFMA; setprio(0);
//   vmcnt(3) (t<14: t+1 resident, t+2's 3 in flight) / vmcnt(0) (t==14);
//   barrier. Safety: buf[(t+2)%3]==buf[(t-1)%3], reads retired at the
//   bottom-of-(t-1) barrier (same proof as R15).
// ===========================================================================
__global__ __launch_bounds__(512, 4) void gemm_bf16(
    const u16* __restrict__ A, const u16* __restrict__ Bm,
    const float* __restrict__ bq, const float* __restrict__ bk,
    const float* __restrict__ bv,
    u16* __restrict__ qb, u16* __restrict__ kvb)
{
    // XCD-chunked bijective remap (8 XCDs, 1056 = 8*132 blocks)
    const int bid = blockIdx.x;
    const int wg  = (bid & 7) * 132 + (bid >> 3);
    const int m0  = (wg & 15) << 7;     // m fastest within an XCD
    const int n0  = (wg >> 4) << 8;     // 66 n-tiles of 256

    __shared__ u16 As[3][128 * 32];     // 3 x 8 KB
    __shared__ u16 Bs[3][256 * 32];     // 3 x 16 KB

    const int tid  = threadIdx.x;
    const int wid  = tid >> 6, lane = tid & 63;
    const int wm   = wid >> 2;          // 0..1  (64-row band)
    const int wn   = wid & 3;           // 0..3  (64-col band)
    const int lr = lane & 15;
    const int qg = lane >> 4;
    const int ksw = ((qg ^ ((lr >> 1) & 3)) << 3);   // swizzled chunk

    const int r0 = tid >> 2;            // staging row 0..127
    const int cc = (tid & 3) << 3;      // staging k-offset (elements)
    const u16* Ag = A  + (size_t)(m0 + r0) * DM + cc;
    const u16* Bg = Bm + (size_t)(n0 + r0) * DM + cc;
    u16* lA = &As[0][0] + tid * 8;      // 512 thr x 8 = 4096 elems = 8KB
    u16* lB = &Bs[0][0] + tid * 8;

    // stage k-tile t2 (32 wide) into buffer c (3 loads/thread)
#define STG(t2, c) do {                                                    \
        const int ko_ = (t2) << 5;                                         \
        gl_lds16(Ag + ko_,                   lA + (c) * 4096);             \
        gl_lds16(Bg + ko_,                   lB + (c) * 8192);             \
        gl_lds16(Bg + ko_ + (size_t)128*DM,  lB + (c) * 8192 + 4096);      \
    } while (0)

    f32x4 acc[4][4];
#pragma unroll
    for (int i = 0; i < 4; ++i)
#pragma unroll
        for (int j = 0; j < 4; ++j) acc[i][j] = (f32x4){0.f, 0.f, 0.f, 0.f};

    STG(0, 0);
    STG(1, 1);
    asm volatile("s_waitcnt vmcnt(3)" ::: "memory");   // tile 0 landed
    bar();

#pragma unroll
    for (int t = 0; t < 16; ++t) {
        const int cur = t % 3;                         // unrolled -> literal
        if (t < 14) STG(t + 2, (t + 2) % 3);           // 2-deep prefetch

        bf16x8 af[4], bfr[4];
#pragma unroll
        for (int i = 0; i < 4; ++i)
            af[i] = *(const bf16x8*)
                &As[cur][((wm << 6) + (i << 4) + lr) * 32 + ksw];
#pragma unroll
        for (int j = 0; j < 4; ++j)
            bfr[j] = *(const bf16x8*)
                &Bs[cur][((wn << 6) + (j << 4) + lr) * 32 + ksw];
        __builtin_amdgcn_s_setprio(1);
#pragma unroll
        for (int i = 0; i < 4; ++i)
#pragma unroll
            for (int j = 0; j < 4; ++j)
                acc[i][j] = __builtin_amdgcn_mfma_f32_16x16x32_bf16(
                    af[i], bfr[j], acc[i][j], 0, 0, 0);
        __builtin_amdgcn_s_setprio(0);

        // counted wait: tile t+1 resident, t+2's loads stay in flight
        if (t < 14)
            asm volatile("s_waitcnt vmcnt(3)" ::: "memory");
        else if (t == 14)
            asm volatile("s_waitcnt vmcnt(0)" ::: "memory");
        if (t < 15) bar();
    }
#undef STG

    if (n0 < 512) {
        // ---- q region (n-tiles 0,1): qb[row][512] ----
#pragma unroll
        for (int i = 0; i < 4; ++i) {
            const int rowb = m0 + (wm << 6) + (i << 4) + (qg << 2);
#pragma unroll
            for (int j = 0; j < 4; ++j) {
                const int col = n0 + (wn << 6) + (j << 4) + lr;
                const float bs = bq[col];
#pragma unroll
                for (int r = 0; r < 4; ++r)
                    qb[(size_t)(rowb + r) * 512 + col] =
                        f2bf(acc[i][j][r] + bs);
            }
        }
    } else {
        // ---- k/v region: kvb panel ((reg*8+h)*16+kslot)*2+b, [l][64] ----
        const int reg = (n0 >= 8704);
        const float* bias = reg ? bv : bk;
        const int t0  = n0 - (reg ? 8704 : 512);   // region-local, 256-aligned
        const int h   = t0 >> 10;                  // head (1024 cols/head)
        const int pb  = ((reg << 3) + h) << 4;     // (reg*8+h)*16
#pragma unroll
        for (int i = 0; i < 4; ++i) {
            const int rowb = m0 + (wm << 6) + (i << 4) + (qg << 2);
#pragma unroll
            for (int j = 0; j < 4; ++j) {
                const int tcol  = (t0 & 1023) + (wn << 6) + (j << 4) + lr;
                const int kslot = tcol >> 6;
                const int oo    = tcol & 63;
                const float bs  = bias[(h << 10) + tcol];
#pragma unroll
                for (int r = 0; r < 4; ++r) {
                    const int row = rowb + r;
                    const int bb  = row >> 10, l2 = row & 1023;
                    kvb[((size_t)(((pb + kslot) << 1) + bb) << 16)
                        + (l2 << 6) + oo] = f2bf(acc[i][j][r] + bs);
                }
            }
        }
    }
}

// ===========================================================================
// Output projection: out(2048x512 fp32) = attnb(2048x512 swz) * Wo^T(512x512
// swz) + bo. 64x64 tiles, grid (8,32) = 256 blocks, 4 waves (16x64 each).
// Counted-vmcnt 3-buffer pipeline + setprio (R17).
// ===========================================================================
__global__ __launch_bounds__(256, 4) void gemm_out(
    const u16* __restrict__ A, const u16* __restrict__ Bm,
    const float* __restrict__ bias, float* __restrict__ C)
{
    __shared__ u16 As[3][64 * 32];      // 3 x 4 KB
    __shared__ u16 Bs[3][64 * 32];      // 3 x 4 KB

    const int tid  = threadIdx.x;
    const int wave = tid >> 6, lane = tid & 63;
    const int m0 = blockIdx.y << 6, n0 = blockIdx.x << 6;
    const int r0 = tid >> 2, cc = (tid & 3) << 3;
    const int mw = wave << 4;           // wave's 16-row band
    const int lr = lane & 15, qg = lane >> 4;
    const int ksw = ((qg ^ ((lr >> 1) & 3)) << 3);

    const u16* Ag = A  + (size_t)(m0 + r0) * DM + cc;
    const u16* Bg = Bm + (size_t)(n0 + r0) * DM + cc;
    u16* lA = &As[0][0] + tid * 8;
    u16* lB = &Bs[0][0] + tid * 8;

#define STG(t2, c) do {                                                    \
        const int ko_ = (t2) << 5;                                         \
        gl_lds16(Ag + ko_, lA + (c) * 2048);                               \
        gl_lds16(Bg + ko_, lB + (c) * 2048);                               \
    } while (0)

    f32x4 acc[4];
#pragma unroll
    for (int j = 0; j < 4; ++j) acc[j] = (f32x4){0.f, 0.f, 0.f, 0.f};

    STG(0, 0);
    STG(1, 1);
    asm volatile("s_waitcnt vmcnt(2)" ::: "memory");   // tile 0 landed
    bar();

#pragma unroll
    for (int t = 0; t < 16; ++t) {
        const int cur = t % 3;
        if (t < 14) STG(t + 2, (t + 2) % 3);

        bf16x8 af = *(const bf16x8*)&As[cur][(mw + lr) * 32 + ksw];
        __builtin_amdgcn_s_setprio(1);
#pragma unroll
        for (int j = 0; j < 4; ++j) {
            bf16x8 bfr = *(const bf16x8*)&Bs[cur][((j << 4) + lr) * 32 + ksw];
            acc[j] = __builtin_amdgcn_mfma_f32_16x16x32_bf16(af, bfr, acc[j], 0, 0, 0);
        }
        __builtin_amdgcn_s_setprio(0);

        if (t < 14)
            asm volatile("s_waitcnt vmcnt(2)" ::: "memory");
        else if (t == 14)
            asm volatile("s_waitcnt vmcnt(0)" ::: "memory");
        if (t < 15) bar();
    }
#undef STG

    // C row = m0+mw+4qg+r, col = n0+16j+lr
#pragma unroll
    for (int j = 0; j < 4; ++j) {
        const int col = n0 + (j << 4) + lr;
        const float bs = bias[col];
#pragma unroll
        for (int r = 0; r < 4; ++r)
            C[(size_t)(m0 + mw + (qg << 2) + r) * DM + col] = acc[j][r] + bs;
    }
}

// ===========================================================================
// fp32 -> bf16 + swizzle. One thread per 8-elem chunk: 32B read, 16B write,
// both coalesced (the XOR permutes chunks within a 64B line).
// Chunks (row*64): x 131072 | [Wq|Wk|Wv] 1081344 | Wo 32768
// Total 1245184 = 4864 blocks x 256.
// ===========================================================================
__global__ void cvt_swz(const float* __restrict__ x,  const float* __restrict__ Wq,
                        const float* __restrict__ Wk, const float* __restrict__ Wv,
                        const float* __restrict__ Wo,
                        u16* __restrict__ xb, u16* __restrict__ wb,
                        u16* __restrict__ wob)
{
    const int i = blockIdx.x * 256 + threadIdx.x;
    const float* src; u16* dst; int t;
    if (i < 131072) {
        t = i;
        src = x;  dst = xb;
    } else if (i < 1212416) {
        t = i - 131072;
        const int row = t >> 6;
        if      (row <  512) src = Wq;
        else if (row < 8704) src = Wk - (size_t)512 * DM;
        else                 src = Wv - (size_t)8704 * DM;
        dst = wb;
    } else {
        t = i - 1212416;
        src = Wo; dst = wob;
    }
    const int row = t >> 6;              // 64 chunks per row
    const int c8  = t & 63;              // output chunk within row
    const int s   = (row >> 1) & 3;
    const int oc  = (c8 & ~3) | ((c8 & 3) ^ s);   // source chunk
    const float* p = src + (size_t)row * DM + (oc << 3);
    float4 v0 = *(const float4*)p;
    float4 v1 = *(const float4*)(p + 4);
    ushort8v o = { f2bf(v0.x), f2bf(v0.y), f2bf(v0.z), f2bf(v0.w),
                   f2bf(v1.x), f2bf(v1.y), f2bf(v1.z), f2bf(v1.w) };
    *(ushort8v*)(dst + (size_t)row * DM + (c8 << 3)) = o;
}

// ===========================================================================
// attention gather, K-SPLIT two-phase register-resident, panel layout (R18).
// 256 thr = 16 l's x 8 o-groups x 2 k-halves; grid = B*H*(L/16) = 1024
// -> 4 blk/CU, 4 waves/SIMD, 8-load latency chains.
// Lane map: j = lane&7, ks = lane bit 3, l-part = lane>>4.
// Logit reduce over j via shfl_xor(1,2,4); k-half combine via shfl_xor(8):
// max combined BEFORE exp (no rescale), sum and acc pairwise-added;
// ks=0 lanes store.
// ===========================================================================
__global__ __launch_bounds__(256, 4) void attn_bf16(
    const u16* __restrict__ qb,     // (B*L, 512) bf16
    const u16* __restrict__ kvb,    // panels, see gemm_bf16
    const float* __restrict__ bk,   // (H,K,64) fp32
    const float* __restrict__ bv,
    u16* __restrict__ attnb)        // (B,L,512) bf16 swizzled
{
    const int tid = threadIdx.x;
    const int j   = tid & 7;         // o-group (8 o's)
    const int ks  = (tid >> 3) & 1;  // k-half: k = ks*8 + kk
    const int ll  = tid >> 4;        // 0..15
    const int bid = blockIdx.x;
    const int h = bid & 7;
    const int t = (bid >> 3) & 63;   // L/16 = 64 l-tiles
    const int b = bid >> 9;
    const int l = (t << 4) + ll;
    const int dil = c_dil[h];
    const int kof = ks << 3;         // 0 or 8

    const int hko = h * (KT * HW);   // bias head offset

    float qf[8];
    {
        ushort8v qv = *(const ushort8v*)(qb + (size_t)(b * LL + l) * 512
                                         + h * HW + (j << 3));
#pragma unroll
        for (int z = 0; z < 8; ++z) qf[z] = bf2f(qv[z]);
    }

    // panel bases: K panel p = (h*16+k)*2+b, V panel p = ((8+h)*16+k)*2+b
    const u16* kbase = kvb + ((size_t)(((h << 4) << 1) + b) << 16) + (j << 3);
    const u16* vbase = kbase + ((size_t)(8 << 4) << 17);   // +8*16 panels *2*65536

    // ---- phase 1: this half's 8 k loads in flight, then logits ----
    ushort8v kr[8];
#pragma unroll
    for (int kk = 0; kk < 8; ++kk) {
        const int k = kof + kk;
        const int src = l - (KT - 1 - k) * dil;
        if (src >= 0)
            kr[kk] = *(const ushort8v*)(kbase + ((size_t)k << 17) + (src << 6));
    }

    float lg[8];
#pragma unroll
    for (int kk = 0; kk < 8; ++kk) {
        const int k = kof + kk;
        const int src = l - (KT - 1 - k) * dil;
        float p = 0.f;
        if (src >= 0) {
#pragma unroll
            for (int z = 0; z < 8; ++z) p += qf[z] * bf2f(kr[kk][z]);
        } else {
            const float* bkp = bk + hko + k * HW + (j << 3);
#pragma unroll
            for (int z = 0; z < 8; ++z) p += qf[z] * bkp[z];
        }
        p += __shfl_xor(p, 1);
        p += __shfl_xor(p, 2);
        p += __shfl_xor(p, 4);
        lg[kk] = p;
    }

    // ---- softmax: local 8, then combine across k-half pair (lane bit 3) ----
    float m = lg[0];
#pragma unroll
    for (int kk = 1; kk < 8; ++kk) m = fmaxf(m, lg[kk]);
    m = fmaxf(m, __shfl_xor(m, 8));          // global max over 16 k's
    float s = 0.f;
#pragma unroll
    for (int kk = 0; kk < 8; ++kk) { lg[kk] = __expf(lg[kk] - m); s += lg[kk]; }
    s += __shfl_xor(s, 8);                   // global sum
    const float inv = 1.f / s;

    // ---- phase 2: this half's 8 v loads in flight, weighted accumulate ----
    ushort8v vr[8];
#pragma unroll
    for (int kk = 0; kk < 8; ++kk) {
        const int k = kof + kk;
        const int src = l - (KT - 1 - k) * dil;
        if (src >= 0)
            vr[kk] = *(const ushort8v*)(vbase + ((size_t)k << 17) + (src << 6));
    }

    float acc[8];
#pragma unroll
    for (int z = 0; z < 8; ++z) acc[z] = 0.f;
#pragma unroll
    for (int kk = 0; kk < 8; ++kk) {
        const int k = kof + kk;
        const int src = l - (KT - 1 - k) * dil;
        const float sc = lg[kk] * inv;
        if (src >= 0) {
#pragma unroll
            for (int z = 0; z < 8; ++z) acc[z] = fmaf(sc, bf2f(vr[kk][z]), acc[z]);
        } else {
            const float* bvp = bv + hko + k * HW + (j << 3);
#pragma unroll
            for (int z = 0; z < 8; ++z) acc[z] = fmaf(sc, bvp[z], acc[z]);
        }
    }

    // combine the two k-halves (both lanes end up with the total)
#pragma unroll
    for (int z = 0; z < 8; ++z) acc[z] += __shfl_xor(acc[z], 8);

    if (ks == 0) {
        ushort8v o;
#pragma unroll
        for (int z = 0; z < 8; ++z) o[z] = f2bf(acc[z] * 0.125f);
        const int row = b * LL + l;
        const int k8 = h * 8 + j;
        const int sw = ((k8 & 3) ^ ((l >> 1) & 3)) << 3;
        *(ushort8v*)(attnb + (size_t)row * DM + ((k8 >> 2) << 5) + sw) = o;
    }
}

// ===========================================================================
// ------------------- round-1 fp32 fallback (small ws) ----------------------
// ===========================================================================
__global__ __launch_bounds__(256, 2) void gemm_nt_bias(
    const float* __restrict__ A, const float* __restrict__ Bm,
    const float* __restrict__ bias, float* __restrict__ C,
    int M, int N, int Kd)
{
    __shared__ float As[16][68];
    __shared__ float Bs[16][68];
    const int tid = threadIdx.x;
    const int tx = tid & 15, ty = tid >> 4;
    const int r0 = blockIdx.y << 6, c0 = blockIdx.x << 6;
    const int lr = tid >> 2, k4 = (tid & 3) << 2;
    const float* Ap = A  + (size_t)(r0 + lr) * Kd + k4;
    const float* Bp = Bm + (size_t)(c0 + lr) * Kd + k4;
    float acc[4][4];
#pragma unroll
    for (int i = 0; i < 4; ++i)
#pragma unroll
        for (int j = 0; j < 4; ++j) acc[i][j] = 0.f;
    for (int d0 = 0; d0 < Kd; d0 += 16) {
        float4 av = *(const float4*)(Ap + d0);
        float4 bv = *(const float4*)(Bp + d0);
        As[k4 + 0][lr] = av.x; As[k4 + 1][lr] = av.y;
        As[k4 + 2][lr] = av.z; As[k4 + 3][lr] = av.w;
        Bs[k4 + 0][lr] = bv.x; Bs[k4 + 1][lr] = bv.y;
        Bs[k4 + 2][lr] = bv.z; Bs[k4 + 3][lr] = bv.w;
        __syncthreads();
#pragma unroll
        for (int dd = 0; dd < 16; ++dd) {
            float4 a4 = *(const float4*)&As[dd][ty << 2];
            float4 b4 = *(const float4*)&Bs[dd][tx << 2];
            float ar[4] = {a4.x, a4.y, a4.z, a4.w};
            float br[4] = {b4.x, b4.y, b4.z, b4.w};
#pragma unroll
            for (int i = 0; i < 4; ++i)
#pragma unroll
                for (int j = 0; j < 4; ++j)
                    acc[i][j] = fmaf(ar[i], br[j], acc[i][j]);
        }
        __syncthreads();
    }
#pragma unroll
    for (int i = 0; i < 4; ++i) {
        float4 o;
        const int c = c0 + (tx << 2);
        o.x = acc[i][0] + bias[c + 0];
        o.y = acc[i][1] + bias[c + 1];
        o.z = acc[i][2] + bias[c + 2];
        o.w = acc[i][3] + bias[c + 3];
        *(float4*)&C[(size_t)(r0 + (ty << 2) + i) * N + c] = o;
    }
}

__device__ __forceinline__ void tile_gemm_f32(
    const float* __restrict__ xb, int src, bool ok,
    const float* __restrict__ wrow,
    int lr, int k4, int tx, int ty,
    float (&As)[16][68], float (&Ws)[16][68], float (&acc)[4][4])
{
#pragma unroll
    for (int i = 0; i < 4; ++i)
#pragma unroll
        for (int j = 0; j < 4; ++j) acc[i][j] = 0.f;
    const float* xrow = xb + (size_t)(ok ? src : 0) * DM + k4;
    for (int d0 = 0; d0 < DM; d0 += 16) {
        float4 av = make_float4(0.f, 0.f, 0.f, 0.f);
        if (ok) av = *(const float4*)(xrow + d0);
        float4 wv = *(const float4*)(wrow + d0);
        As[k4 + 0][lr] = av.x; As[k4 + 1][lr] = av.y;
        As[k4 + 2][lr] = av.z; As[k4 + 3][lr] = av.w;
        Ws[k4 + 0][lr] = wv.x; Ws[k4 + 1][lr] = wv.y;
        Ws[k4 + 2][lr] = wv.z; Ws[k4 + 3][lr] = wv.w;
        __syncthreads();
#pragma unroll
        for (int dd = 0; dd < 16; ++dd) {
            float4 a4 = *(const float4*)&As[dd][ty << 2];
            float4 b4 = *(const float4*)&Ws[dd][tx << 2];
            float ar[4] = {a4.x, a4.y, a4.z, a4.w};
            float br[4] = {b4.x, b4.y, b4.z, b4.w};
#pragma unroll
            for (int i = 0; i < 4; ++i)
#pragma unroll
                for (int j = 0; j < 4; ++j)
                    acc[i][j] = fmaf(ar[i], br[j], acc[i][j]);
        }
        __syncthreads();
    }
}

__global__ __launch_bounds__(256, 2) void attn_kernel(
    const float* __restrict__ x, const float* __restrict__ q,
    const float* __restrict__ Wk, const float* __restrict__ bk,
    const float* __restrict__ Wv, const float* __restrict__ bv,
    float* __restrict__ attn)
{
    __shared__ float As[16][68];
    __shared__ float Ws[16][68];
    __shared__ float qs[64][68];
    __shared__ float lg[64][17];
    __shared__ float red[64][17];
    const int tid = threadIdx.x;
    const int tx = tid & 15, ty = tid >> 4;
    const int bid = blockIdx.x;
    const int h = bid & 7, t = (bid >> 3) & 15, b = bid >> 7;
    const int l0 = t << 6;
    const int dil = c_dil[h];
    const int lr = tid >> 2, k4 = (tid & 3) << 2;
    for (int i = tid; i < 64 * 16; i += 256) {
        int l = i >> 4, o4 = (i & 15) << 2;
        float4 v = *(const float4*)&q[((size_t)(b * LL + l0 + l) * HH + h) * HW + o4];
        *(float4*)&qs[l][o4] = v;
    }
    const float* xb  = x  + (size_t)b * LL * DM;
    const float* Wkh = Wk + (size_t)h * KT * HW * DM;
    const float* Wvh = Wv + (size_t)h * KT * HW * DM;
    const float* bkh = bk + h * KT * HW;
    const float* bvh = bv + h * KT * HW;
    float acc[4][4];
    for (int kk = 0; kk < KT; ++kk) {
        const int src = l0 + lr - (KT - 1 - kk) * dil;
        const bool ok = (src >= 0) && (src < LL);
        tile_gemm_f32(xb, src, ok, Wkh + (size_t)(kk * HW + lr) * DM + k4,
                      lr, k4, tx, ty, As, Ws, acc);
        const float* bkp = bkh + kk * HW + (tx << 2);
#pragma unroll
        for (int i = 0; i < 4; ++i) {
            float p = 0.f;
#pragma unroll
            for (int j = 0; j < 4; ++j)
                p += (acc[i][j] + bkp[j]) * qs[(ty << 2) + i][(tx << 2) + j];
            red[(ty << 2) + i][tx] = p;
        }
        __syncthreads();
        if (tid < 64) {
            float s = 0.f;
#pragma unroll
            for (int u = 0; u < 16; ++u) s += red[tid][u];
            lg[tid][kk] = s;
        }
        __syncthreads();
    }
    if (tid < 64) {
        float m = lg[tid][0];
#pragma unroll
        for (int u = 1; u < KT; ++u) m = fmaxf(m, lg[tid][u]);
        float s = 0.f;
#pragma unroll
        for (int u = 0; u < KT; ++u) {
            float e = expf(lg[tid][u] - m);
            lg[tid][u] = e; s += e;
        }
        float inv = 1.f / s;
#pragma unroll
        for (int u = 0; u < KT; ++u) lg[tid][u] *= inv;
    }
    __syncthreads();
    float vacc[4][4];
#pragma unroll
    for (int i = 0; i < 4; ++i)
#pragma unroll
        for (int j = 0; j < 4; ++j) vacc[i][j] = 0.f;
    for (int kk = 0; kk < KT; ++kk) {
        const int src = l0 + lr - (KT - 1 - kk) * dil;
        const bool ok = (src >= 0) && (src < LL);
        tile_gemm_f32(xb, src, ok, Wvh + (size_t)(kk * HW + lr) * DM + k4,
                      lr, k4, tx, ty, As, Ws, acc);
        const float* bvp = bvh + kk * HW + (tx << 2);
#pragma unroll
        for (int i = 0; i < 4; ++i) {
            float sc = lg[(ty << 2) + i][kk];
#pragma unroll
            for (int j = 0; j < 4; ++j)
                vacc[i][j] = fmaf(sc, acc[i][j] + bvp[j], vacc[i][j]);
        }
    }
#pragma unroll
    for (int i = 0; i < 4; ++i) {
        float4 o;
        o.x = vacc[i][0] * 0.125f;
        o.y = vacc[i][1] * 0.125f;
        o.z = vacc[i][2] * 0.125f;
        o.w = vacc[i][3] * 0.125f;
        *(float4*)&attn[((size_t)(b * LL + l0 + (ty << 2) + i) * HH + h) * HW + (tx << 2)] = o;
    }
}

// ===========================================================================
extern "C" void kernel_launch(void* const* d_in, const int* in_sizes, int n_in,
                              void* d_out, int out_size, void* d_ws, size_t ws_size,
                              hipStream_t stream)
{
    const float* x  = (const float*)d_in[0];
    const float* Wq = (const float*)d_in[1];
    const float* bq = (const float*)d_in[2];
    const float* Wk = (const float*)d_in[3];
    const float* bk = (const float*)d_in[4];
    const float* Wv = (const float*)d_in[5];
    const float* bv = (const float*)d_in[6];
    const float* Wo = (const float*)d_in[7];
    const float* bo = (const float*)d_in[8];
    float* out = (float*)d_out;

    const int M = BD * LL;  // 2048

    // ws layout (ushort elements) for the fast path
    const size_t N_X   = (size_t)BD * LL * DM;            //  1,048,576
    const size_t N_WB  = (size_t)NQKV * DM;               //  8,650,752
    const size_t N_WO  = (size_t)DM * DM;                 //    262,144
    const size_t N_QKV = (size_t)M * NQKV;                // 34,603,008 = qb+kvb
    const size_t NEED  = (N_X + N_WB + N_WO + N_QKV + N_X) * 2;

    if (ws_size >= NEED) {
        u16* xb    = (u16*)d_ws;
        u16* wb    = xb    + N_X;      // [Wq|Wk|Wv] swizzled, 16896 x 512
        u16* wob   = wb    + N_WB;
        u16* qb    = wob   + N_WO;     // q: 2048 x 512
        u16* kvb   = qb    + N_X;      // k/v panels: 512 x 65536
        u16* attnb = qb    + N_QKV;

        cvt_swz<<<4864, 256, 0, stream>>>(x, Wq, Wk, Wv, Wo, xb, wb, wob);

        // q/k/v projections (128x256, 8-wave, counted-vmcnt 3-buf, XCD remap)
        gemm_bf16<<<dim3(1056), 512, 0, stream>>>(
            xb, wb, bq, bk, bv, qb, kvb);

        // k-split two-phase gather -> attnb (swizzled); grid B*H*(L/16)
        attn_bf16<<<BD * HH * (LL / 16), 256, 0, stream>>>(
            qb, kvb, bk, bv, attnb);

        // out = attnb * Wo^T + bo -> fp32
        gemm_out<<<dim3(8, 32), 256, 0, stream>>>(attnb, wob, bo, out);
    } else {
        // fp32 fallback (round-1 path, 8 MB ws)
        float* qws = (float*)d_ws;
        float* aws = qws + (size_t)BD * LL * HH * HW;
        gemm_nt_bias<<<dim3((HH * HW) / 64, M / 64), 256, 0, stream>>>(
            x, Wq, bq, qws, M, HH * HW, DM);
        attn_kernel<<<BD * HH * (LL / 64), 256, 0, stream>>>(
            x, qws, Wk, bk, Wv, bv, aws);
        gemm_nt_bias<<<dim3(DM / 64, M / 64), 256, 0, stream>>>(
            aws, Wo, bo, out, M, DM, HH * HW);
    }
}

// Round 11
// 161.457 us; speedup vs baseline: 1.0563x; 1.0008x over previous
//
#include <hip/hip_runtime.h>

// LCSA: dilated local-window self-attention.
// B=2, L=1024, D=512, H=8, HEAD_W=64, KERNEL=16, dilations {1,1,2,2,4,4,8,8},
// MODE=forward -> src(l,k) = l - (15-k)*dil, zero-padded outside [0,L).
//
// R20 (FINAL, consolidation): best-measured component set.
//   gemm_bf16: R17 config (128x128, BK=32, counted-vmcnt 3-buf, setprio,
//     XCD remap, panel epilogue) - 53.4us, best of NINE variants. All nine
//     (R10-R19: occupancy 15-31%, LDS traffic +/-25%, L2 locality, barrier
//     structure, vmcnt discipline, setprio) pin MfmaUtil at 23-26% = 663 TF
//     == the documented 2-phase structural ceiling (m248: 655 TF). Path
//     past it = full 8-phase fine-interleave; at K=512 projects only
//     ~6-8us and is a race-prone sync rewrite -> not taken blind.
//   attn_bf16: R18 k-split gather. Attn is within ~4us of its 71MB
//     compulsory-BW floor (zero K/V reuse: each gathered vector read
//     exactly once -- proven by R14 layout-null).
//   gemm_out/cvt_swz: R17/R10 (small-kernel floors).
//   Residual ~50-70us of dur_us is harness fixed cost (memsets/restores/
//   launch drain), insensitive to all nine kernel-level interventions.
// Fallback: round-1 fp32 path (8 MB ws).

#define BD 2
#define LL 1024
#define DM 512
#define HH 8
#define KT 16
#define HW 64

#define NQKV 16896          // legacy total: 512 q + 8192 k + 8192 v

typedef unsigned short u16;
typedef unsigned int u32;
typedef __bf16 bf16x8 __attribute__((ext_vector_type(8)));
typedef float f32x4 __attribute__((ext_vector_type(4)));
typedef unsigned short ushort4v __attribute__((ext_vector_type(4)));
typedef unsigned short ushort8v __attribute__((ext_vector_type(8)));

__constant__ int c_dil[8] = {1, 1, 2, 2, 4, 4, 8, 8};

__device__ __forceinline__ float bf2f(u16 u) {
    return __builtin_bit_cast(float, (u32)u << 16);
}
__device__ __forceinline__ u16 f2bf(float f) {   // round-to-nearest-even
    u32 u = __builtin_bit_cast(u32, f);
    return (u16)((u + 0x7fffu + ((u >> 16) & 1u)) >> 16);
}

// async global->LDS, 16 B per lane; lds dest must be (uniform base + lane*16)
__device__ __forceinline__ void gl_lds16(const u16* g, u16* l) {
    __builtin_amdgcn_global_load_lds(
        (__attribute__((address_space(1))) void*)g,
        (__attribute__((address_space(3))) void*)l, 16, 0, 0);
}

// raw workgroup barrier with compiler memory fences (proven in R11/R15)
__device__ __forceinline__ void bar() {
    asm volatile("" ::: "memory");
    __builtin_amdgcn_s_barrier();
    asm volatile("" ::: "memory");
}

// ===========================================================================
// Fused qkv projection GEMM, counted-vmcnt 3-buffer pipeline, XCD-chunked.
// A(2048x512) * [Wq|Wk|Wv]^T + bias -> qb (2048x512) and kvb panels.
// kvb panel p = ((reg*8 + h)*16 + kslot)*2 + b, 65536 u16 each (1024x64).
// 128x128 tile, BK=32, 4 waves (64x64 each), 16x16x32 MFMA, swizzled A/B,
// LDS 48KB (3 bufs) -> 3 blocks/CU. Grid 2112 linear.  [R17, best-of-9]
//
// Block remap: wg = (bid&7)*264 + (bid>>3) (bijective, 2112 = 8*264),
//   m0 = (wg&15)*128 (fastest within XCD), n0 = (wg>>4)*128.
//
// Pipeline: prologue stages tiles 0,1; vmcnt(4) -> tile0 landed; barrier.
//   iter t: STAGE(t+2 -> buf[(t+2)%3]) (t<14); ds_read buf[t%3];
//   setprio(1); 16 MFMA; setprio(0);
//   vmcnt(4) (t<=13) or vmcnt(0) (t==14); barrier.
// ===========================================================================
__global__ __launch_bounds__(256, 3) void gemm_bf16(
    const u16* __restrict__ A, const u16* __restrict__ Bm,
    const float* __restrict__ bq, const float* __restrict__ bk,
    const float* __restrict__ bv,
    u16* __restrict__ qb, u16* __restrict__ kvb)
{
    // XCD-chunked bijective remap (8 XCDs, 2112 = 8*264 blocks)
    const int bid = blockIdx.x;
    const int wg  = (bid & 7) * 264 + (bid >> 3);
    const int m0  = (wg & 15) << 7;     // m fastest within an XCD
    const int n0  = (wg >> 4) << 7;     // 132 n-tiles of 128

    __shared__ u16 As[3][128 * 32];     // 3 x 8 KB
    __shared__ u16 Bs[3][128 * 32];     // 3 x 8 KB

    const int tid  = threadIdx.x;
    const int wave = tid >> 6, lane = tid & 63;
    const int r0 = tid >> 2;            // staging row 0..63 (round 0)
    const int cc = (tid & 3) << 3;      // staging k-offset (elements)
    const int mw = (wave >> 1) << 6;
    const int nw = (wave & 1) << 6;
    const int lr = lane & 15;
    const int qg = lane >> 4;
    const int ksw = ((qg ^ ((lr >> 1) & 3)) << 3);   // swizzled chunk

    const u16* Ag = A  + (size_t)(m0 + r0) * DM + cc;
    const u16* Bg = Bm + (size_t)(n0 + r0) * DM + cc;
    u16* lA = &As[0][0] + tid * 8;
    u16* lB = &Bs[0][0] + tid * 8;

    // stage k-tile t2 (32 wide) into buffer c (4 loads/thread)
#define STG(t2, c) do {                                                    \
        const int ko_ = (t2) << 5;                                         \
        gl_lds16(Ag + ko_,                  lA + (c) * 4096);              \
        gl_lds16(Ag + ko_ + (size_t)64*DM,  lA + (c) * 4096 + 2048);       \
        gl_lds16(Bg + ko_,                  lB + (c) * 4096);              \
        gl_lds16(Bg + ko_ + (size_t)64*DM,  lB + (c) * 4096 + 2048);       \
    } while (0)

    f32x4 acc[4][4];
#pragma unroll
    for (int i = 0; i < 4; ++i)
#pragma unroll
        for (int j = 0; j < 4; ++j) acc[i][j] = (f32x4){0.f, 0.f, 0.f, 0.f};

    STG(0, 0);
    STG(1, 1);
    asm volatile("s_waitcnt vmcnt(4)" ::: "memory");   // tile 0 landed
    bar();

#pragma unroll
    for (int t = 0; t < 16; ++t) {
        const int cur = t % 3;                         // unrolled -> literal
        if (t < 14) STG(t + 2, (t + 2) % 3);           // 2-deep prefetch

        bf16x8 af[4], bfr[4];
#pragma unroll
        for (int i = 0; i < 4; ++i)
            af[i] = *(const bf16x8*)&As[cur][(mw + (i << 4) + lr) * 32 + ksw];
#pragma unroll
        for (int j = 0; j < 4; ++j)
            bfr[j] = *(const bf16x8*)&Bs[cur][(nw + (j << 4) + lr) * 32 + ksw];
        __builtin_amdgcn_s_setprio(1);
#pragma unroll
        for (int i = 0; i < 4; ++i)
#pragma unroll
            for (int j = 0; j < 4; ++j)
                acc[i][j] = __builtin_amdgcn_mfma_f32_16x16x32_bf16(
                    af[i], bfr[j], acc[i][j], 0, 0, 0);
        __builtin_amdgcn_s_setprio(0);

        // counted wait: tile t+1 resident, t+2's loads stay in flight
        if (t < 14)
            asm volatile("s_waitcnt vmcnt(4)" ::: "memory");
        else if (t == 14)
            asm volatile("s_waitcnt vmcnt(0)" ::: "memory");
        if (t < 15) bar();
    }
#undef STG

    if (n0 < 512) {
        // ---- q region: qb[row][512] ----
#pragma unroll
        for (int i = 0; i < 4; ++i) {
            const int rowb = m0 + mw + (i << 4) + (qg << 2);
#pragma unroll
            for (int j = 0; j < 4; ++j) {
                const int col = n0 + nw + (j << 4) + lr;
                const float bs = bq[col];
#pragma unroll
                for (int r = 0; r < 4; ++r)
                    qb[(size_t)(rowb + r) * 512 + col] =
                        f2bf(acc[i][j][r] + bs);
            }
        }
    } else {
        // ---- k/v region: kvb panel ((reg*8+h)*16+kslot)*2+b, [l][64] ----
        const int reg = (n0 >= 8704);
        const float* bias = reg ? bv : bk;
        const int t0  = n0 - (reg ? 8704 : 512);   // region-local, 128-aligned
        const int h   = t0 >> 10;                  // tile within one head
        const int pb  = ((reg << 3) + h) << 4;     // (reg*8+h)*16
#pragma unroll
        for (int i = 0; i < 4; ++i) {
            const int rowb = m0 + mw + (i << 4) + (qg << 2);
#pragma unroll
            for (int j = 0; j < 4; ++j) {
                const int tcol  = (t0 & 1023) + nw + (j << 4) + lr; // head-local
                const int kslot = tcol >> 6;
                const int oo    = tcol & 63;
                const float bs  = bias[(h << 10) + tcol];
#pragma unroll
                for (int r = 0; r < 4; ++r) {
                    const int row = rowb + r;
                    const int bb  = row >> 10, l2 = row & 1023;
                    kvb[((size_t)(((pb + kslot) << 1) + bb) << 16)
                        + (l2 << 6) + oo] = f2bf(acc[i][j][r] + bs);
                }
            }
        }
    }
}

// ===========================================================================
// Output projection: out(2048x512 fp32) = attnb(2048x512 swz) * Wo^T(512x512
// swz) + bo. 64x64 tiles, grid (8,32) = 256 blocks, 4 waves (16x64 each).
// Counted-vmcnt 3-buffer pipeline + setprio (R17).
// ===========================================================================
__global__ __launch_bounds__(256, 4) void gemm_out(
    const u16* __restrict__ A, const u16* __restrict__ Bm,
    const float* __restrict__ bias, float* __restrict__ C)
{
    __shared__ u16 As[3][64 * 32];      // 3 x 4 KB
    __shared__ u16 Bs[3][64 * 32];      // 3 x 4 KB

    const int tid  = threadIdx.x;
    const int wave = tid >> 6, lane = tid & 63;
    const int m0 = blockIdx.y << 6, n0 = blockIdx.x << 6;
    const int r0 = tid >> 2, cc = (tid & 3) << 3;
    const int mw = wave << 4;           // wave's 16-row band
    const int lr = lane & 15, qg = lane >> 4;
    const int ksw = ((qg ^ ((lr >> 1) & 3)) << 3);

    const u16* Ag = A  + (size_t)(m0 + r0) * DM + cc;
    const u16* Bg = Bm + (size_t)(n0 + r0) * DM + cc;
    u16* lA = &As[0][0] + tid * 8;
    u16* lB = &Bs[0][0] + tid * 8;

#define STG(t2, c) do {                                                    \
        const int ko_ = (t2) << 5;                                         \
        gl_lds16(Ag + ko_, lA + (c) * 2048);                               \
        gl_lds16(Bg + ko_, lB + (c) * 2048);                               \
    } while (0)

    f32x4 acc[4];
#pragma unroll
    for (int j = 0; j < 4; ++j) acc[j] = (f32x4){0.f, 0.f, 0.f, 0.f};

    STG(0, 0);
    STG(1, 1);
    asm volatile("s_waitcnt vmcnt(2)" ::: "memory");   // tile 0 landed
    bar();

#pragma unroll
    for (int t = 0; t < 16; ++t) {
        const int cur = t % 3;
        if (t < 14) STG(t + 2, (t + 2) % 3);

        bf16x8 af = *(const bf16x8*)&As[cur][(mw + lr) * 32 + ksw];
        __builtin_amdgcn_s_setprio(1);
#pragma unroll
        for (int j = 0; j < 4; ++j) {
            bf16x8 bfr = *(const bf16x8*)&Bs[cur][((j << 4) + lr) * 32 + ksw];
            acc[j] = __builtin_amdgcn_mfma_f32_16x16x32_bf16(af, bfr, acc[j], 0, 0, 0);
        }
        __builtin_amdgcn_s_setprio(0);

        if (t < 14)
            asm volatile("s_waitcnt vmcnt(2)" ::: "memory");
        else if (t == 14)
            asm volatile("s_waitcnt vmcnt(0)" ::: "memory");
        if (t < 15) bar();
    }
#undef STG

    // C row = m0+mw+4qg+r, col = n0+16j+lr
#pragma unroll
    for (int j = 0; j < 4; ++j) {
        const int col = n0 + (j << 4) + lr;
        const float bs = bias[col];
#pragma unroll
        for (int r = 0; r < 4; ++r)
            C[(size_t)(m0 + mw + (qg << 2) + r) * DM + col] = acc[j][r] + bs;
    }
}

// ===========================================================================
// fp32 -> bf16 + swizzle. One thread per 8-elem chunk: 32B read, 16B write,
// both coalesced (the XOR permutes chunks within a 64B line).
// Chunks (row*64): x 131072 | [Wq|Wk|Wv] 1081344 | Wo 32768
// Total 1245184 = 4864 blocks x 256.
// ===========================================================================
__global__ void cvt_swz(const float* __restrict__ x,  const float* __restrict__ Wq,
                        const float* __restrict__ Wk, const float* __restrict__ Wv,
                        const float* __restrict__ Wo,
                        u16* __restrict__ xb, u16* __restrict__ wb,
                        u16* __restrict__ wob)
{
    const int i = blockIdx.x * 256 + threadIdx.x;
    const float* src; u16* dst; int t;
    if (i < 131072) {
        t = i;
        src = x;  dst = xb;
    } else if (i < 1212416) {
        t = i - 131072;
        const int row = t >> 6;
        if      (row <  512) src = Wq;
        else if (row < 8704) src = Wk - (size_t)512 * DM;
        else                 src = Wv - (size_t)8704 * DM;
        dst = wb;
    } else {
        t = i - 1212416;
        src = Wo; dst = wob;
    }
    const int row = t >> 6;              // 64 chunks per row
    const int c8  = t & 63;              // output chunk within row
    const int s   = (row >> 1) & 3;
    const int oc  = (c8 & ~3) | ((c8 & 3) ^ s);   // source chunk
    const float* p = src + (size_t)row * DM + (oc << 3);
    float4 v0 = *(const float4*)p;
    float4 v1 = *(const float4*)(p + 4);
    ushort8v o = { f2bf(v0.x), f2bf(v0.y), f2bf(v0.z), f2bf(v0.w),
                   f2bf(v1.x), f2bf(v1.y), f2bf(v1.z), f2bf(v1.w) };
    *(ushort8v*)(dst + (size_t)row * DM + (c8 << 3)) = o;
}

// ===========================================================================
// attention gather, K-SPLIT two-phase register-resident, panel layout (R18).
// 256 thr = 16 l's x 8 o-groups x 2 k-halves; grid = B*H*(L/16) = 1024
// -> 4 blk/CU, 4 waves/SIMD, 8-load latency chains.
// Lane map: j = lane&7, ks = lane bit 3, l-part = lane>>4.
// Logit reduce over j via shfl_xor(1,2,4); k-half combine via shfl_xor(8):
// max combined BEFORE exp (no rescale), sum and acc pairwise-added;
// ks=0 lanes store. Reads are compulsory-unique (~71MB) -> near BW floor.
// ===========================================================================
__global__ __launch_bounds__(256, 4) void attn_bf16(
    const u16* __restrict__ qb,     // (B*L, 512) bf16
    const u16* __restrict__ kvb,    // panels, see gemm_bf16
    const float* __restrict__ bk,   // (H,K,64) fp32
    const float* __restrict__ bv,
    u16* __restrict__ attnb)        // (B,L,512) bf16 swizzled
{
    const int tid = threadIdx.x;
    const int j   = tid & 7;         // o-group (8 o's)
    const int ks  = (tid >> 3) & 1;  // k-half: k = ks*8 + kk
    const int ll  = tid >> 4;        // 0..15
    const int bid = blockIdx.x;
    const int h = bid & 7;
    const int t = (bid >> 3) & 63;   // L/16 = 64 l-tiles
    const int b = bid >> 9;
    const int l = (t << 4) + ll;
    const int dil = c_dil[h];
    const int kof = ks << 3;         // 0 or 8

    const int hko = h * (KT * HW);   // bias head offset

    float qf[8];
    {
        ushort8v qv = *(const ushort8v*)(qb + (size_t)(b * LL + l) * 512
                                         + h * HW + (j << 3));
#pragma unroll
        for (int z = 0; z < 8; ++z) qf[z] = bf2f(qv[z]);
    }

    // panel bases: K panel p = (h*16+k)*2+b, V panel p = ((8+h)*16+k)*2+b
    const u16* kbase = kvb + ((size_t)(((h << 4) << 1) + b) << 16) + (j << 3);
    const u16* vbase = kbase + ((size_t)(8 << 4) << 17);   // +8*16 panels *2*65536

    // ---- phase 1: this half's 8 k loads in flight, then logits ----
    ushort8v kr[8];
#pragma unroll
    for (int kk = 0; kk < 8; ++kk) {
        const int k = kof + kk;
        const int src = l - (KT - 1 - k) * dil;
        if (src >= 0)
            kr[kk] = *(const ushort8v*)(kbase + ((size_t)k << 17) + (src << 6));
    }

    float lg[8];
#pragma unroll
    for (int kk = 0; kk < 8; ++kk) {
        const int k = kof + kk;
        const int src = l - (KT - 1 - k) * dil;
        float p = 0.f;
        if (src >= 0) {
#pragma unroll
            for (int z = 0; z < 8; ++z) p += qf[z] * bf2f(kr[kk][z]);
        } else {
            const float* bkp = bk + hko + k * HW + (j << 3);
#pragma unroll
            for (int z = 0; z < 8; ++z) p += qf[z] * bkp[z];
        }
        p += __shfl_xor(p, 1);
        p += __shfl_xor(p, 2);
        p += __shfl_xor(p, 4);
        lg[kk] = p;
    }

    // ---- softmax: local 8, then combine across k-half pair (lane bit 3) ----
    float m = lg[0];
#pragma unroll
    for (int kk = 1; kk < 8; ++kk) m = fmaxf(m, lg[kk]);
    m = fmaxf(m, __shfl_xor(m, 8));          // global max over 16 k's
    float s = 0.f;
#pragma unroll
    for (int kk = 0; kk < 8; ++kk) { lg[kk] = __expf(lg[kk] - m); s += lg[kk]; }
    s += __shfl_xor(s, 8);                   // global sum
    const float inv = 1.f / s;

    // ---- phase 2: this half's 8 v loads in flight, weighted accumulate ----
    ushort8v vr[8];
#pragma unroll
    for (int kk = 0; kk < 8; ++kk) {
        const int k = kof + kk;
        const int src = l - (KT - 1 - k) * dil;
        if (src >= 0)
            vr[kk] = *(const ushort8v*)(vbase + ((size_t)k << 17) + (src << 6));
    }

    float acc[8];
#pragma unroll
    for (int z = 0; z < 8; ++z) acc[z] = 0.f;
#pragma unroll
    for (int kk = 0; kk < 8; ++kk) {
        const int k = kof + kk;
        const int src = l - (KT - 1 - k) * dil;
        const float sc = lg[kk] * inv;
        if (src >= 0) {
#pragma unroll
            for (int z = 0; z < 8; ++z) acc[z] = fmaf(sc, bf2f(vr[kk][z]), acc[z]);
        } else {
            const float* bvp = bv + hko + k * HW + (j << 3);
#pragma unroll
            for (int z = 0; z < 8; ++z) acc[z] = fmaf(sc, bvp[z], acc[z]);
        }
    }

    // combine the two k-halves (both lanes end up with the total)
#pragma unroll
    for (int z = 0; z < 8; ++z) acc[z] += __shfl_xor(acc[z], 8);

    if (ks == 0) {
        ushort8v o;
#pragma unroll
        for (int z = 0; z < 8; ++z) o[z] = f2bf(acc[z] * 0.125f);
        const int row = b * LL + l;
        const int k8 = h * 8 + j;
        const int sw = ((k8 & 3) ^ ((l >> 1) & 3)) << 3;
        *(ushort8v*)(attnb + (size_t)row * DM + ((k8 >> 2) << 5) + sw) = o;
    }
}

// ===========================================================================
// ------------------- round-1 fp32 fallback (small ws) ----------------------
// ===========================================================================
__global__ __launch_bounds__(256, 2) void gemm_nt_bias(
    const float* __restrict__ A, const float* __restrict__ Bm,
    const float* __restrict__ bias, float* __restrict__ C,
    int M, int N, int Kd)
{
    __shared__ float As[16][68];
    __shared__ float Bs[16][68];
    const int tid = threadIdx.x;
    const int tx = tid & 15, ty = tid >> 4;
    const int r0 = blockIdx.y << 6, c0 = blockIdx.x << 6;
    const int lr = tid >> 2, k4 = (tid & 3) << 2;
    const float* Ap = A  + (size_t)(r0 + lr) * Kd + k4;
    const float* Bp = Bm + (size_t)(c0 + lr) * Kd + k4;
    float acc[4][4];
#pragma unroll
    for (int i = 0; i < 4; ++i)
#pragma unroll
        for (int j = 0; j < 4; ++j) acc[i][j] = 0.f;
    for (int d0 = 0; d0 < Kd; d0 += 16) {
        float4 av = *(const float4*)(Ap + d0);
        float4 bv = *(const float4*)(Bp + d0);
        As[k4 + 0][lr] = av.x; As[k4 + 1][lr] = av.y;
        As[k4 + 2][lr] = av.z; As[k4 + 3][lr] = av.w;
        Bs[k4 + 0][lr] = bv.x; Bs[k4 + 1][lr] = bv.y;
        Bs[k4 + 2][lr] = bv.z; Bs[k4 + 3][lr] = bv.w;
        __syncthreads();
#pragma unroll
        for (int dd = 0; dd < 16; ++dd) {
            float4 a4 = *(const float4*)&As[dd][ty << 2];
            float4 b4 = *(const float4*)&Bs[dd][tx << 2];
            float ar[4] = {a4.x, a4.y, a4.z, a4.w};
            float br[4] = {b4.x, b4.y, b4.z, b4.w};
#pragma unroll
            for (int i = 0; i < 4; ++i)
#pragma unroll
                for (int j = 0; j < 4; ++j)
                    acc[i][j] = fmaf(ar[i], br[j], acc[i][j]);
        }
        __syncthreads();
    }
#pragma unroll
    for (int i = 0; i < 4; ++i) {
        float4 o;
        const int c = c0 + (tx << 2);
        o.x = acc[i][0] + bias[c + 0];
        o.y = acc[i][1] + bias[c + 1];
        o.z = acc[i][2] + bias[c + 2];
        o.w = acc[i][3] + bias[c + 3];
        *(float4*)&C[(size_t)(r0 + (ty << 2) + i) * N + c] = o;
    }
}

__device__ __forceinline__ void tile_gemm_f32(
    const float* __restrict__ xb, int src, bool ok,
    const float* __restrict__ wrow,
    int lr, int k4, int tx, int ty,
    float (&As)[16][68], float (&Ws)[16][68], float (&acc)[4][4])
{
#pragma unroll
    for (int i = 0; i < 4; ++i)
#pragma unroll
        for (int j = 0; j < 4; ++j) acc[i][j] = 0.f;
    const float* xrow = xb + (size_t)(ok ? src : 0) * DM + k4;
    for (int d0 = 0; d0 < DM; d0 += 16) {
        float4 av = make_float4(0.f, 0.f, 0.f, 0.f);
        if (ok) av = *(const float4*)(xrow + d0);
        float4 wv = *(const float4*)(wrow + d0);
        As[k4 + 0][lr] = av.x; As[k4 + 1][lr] = av.y;
        As[k4 + 2][lr] = av.z; As[k4 + 3][lr] = av.w;
        Ws[k4 + 0][lr] = wv.x; Ws[k4 + 1][lr] = wv.y;
        Ws[k4 + 2][lr] = wv.z; Ws[k4 + 3][lr] = wv.w;
        __syncthreads();
#pragma unroll
        for (int dd = 0; dd < 16; ++dd) {
            float4 a4 = *(const float4*)&As[dd][ty << 2];
            float4 b4 = *(const float4*)&Ws[dd][tx << 2];
            float ar[4] = {a4.x, a4.y, a4.z, a4.w};
            float br[4] = {b4.x, b4.y, b4.z, b4.w};
#pragma unroll
            for (int i = 0; i < 4; ++i)
#pragma unroll
                for (int j = 0; j < 4; ++j)
                    acc[i][j] = fmaf(ar[i], br[j], acc[i][j]);
        }
        __syncthreads();
    }
}

__global__ __launch_bounds__(256, 2) void attn_kernel(
    const float* __restrict__ x, const float* __restrict__ q,
    const float* __restrict__ Wk, const float* __restrict__ bk,
    const float* __restrict__ Wv, const float* __restrict__ bv,
    float* __restrict__ attn)
{
    __shared__ float As[16][68];
    __shared__ float Ws[16][68];
    __shared__ float qs[64][68];
    __shared__ float lg[64][17];
    __shared__ float red[64][17];
    const int tid = threadIdx.x;
    const int tx = tid & 15, ty = tid >> 4;
    const int bid = blockIdx.x;
    const int h = bid & 7, t = (bid >> 3) & 15, b = bid >> 7;
    const int l0 = t << 6;
    const int dil = c_dil[h];
    const int lr = tid >> 2, k4 = (tid & 3) << 2;
    for (int i = tid; i < 64 * 16; i += 256) {
        int l = i >> 4, o4 = (i & 15) << 2;
        float4 v = *(const float4*)&q[((size_t)(b * LL + l0 + l) * HH + h) * HW + o4];
        *(float4*)&qs[l][o4] = v;
    }
    const float* xb  = x  + (size_t)b * LL * DM;
    const float* Wkh = Wk + (size_t)h * KT * HW * DM;
    const float* Wvh = Wv + (size_t)h * KT * HW * DM;
    const float* bkh = bk + h * KT * HW;
    const float* bvh = bv + h * KT * HW;
    float acc[4][4];
    for (int kk = 0; kk < KT; ++kk) {
        const int src = l0 + lr - (KT - 1 - kk) * dil;
        const bool ok = (src >= 0) && (src < LL);
        tile_gemm_f32(xb, src, ok, Wkh + (size_t)(kk * HW + lr) * DM + k4,
                      lr, k4, tx, ty, As, Ws, acc);
        const float* bkp = bkh + kk * HW + (tx << 2);
#pragma unroll
        for (int i = 0; i < 4; ++i) {
            float p = 0.f;
#pragma unroll
            for (int j = 0; j < 4; ++j)
                p += (acc[i][j] + bkp[j]) * qs[(ty << 2) + i][(tx << 2) + j];
            red[(ty << 2) + i][tx] = p;
        }
        __syncthreads();
        if (tid < 64) {
            float s = 0.f;
#pragma unroll
            for (int u = 0; u < 16; ++u) s += red[tid][u];
            lg[tid][kk] = s;
        }
        __syncthreads();
    }
    if (tid < 64) {
        float m = lg[tid][0];
#pragma unroll
        for (int u = 1; u < KT; ++u) m = fmaxf(m, lg[tid][u]);
        float s = 0.f;
#pragma unroll
        for (int u = 0; u < KT; ++u) {
            float e = expf(lg[tid][u] - m);
            lg[tid][u] = e; s += e;
        }
        float inv = 1.f / s;
#pragma unroll
        for (int u = 0; u < KT; ++u) lg[tid][u] *= inv;
    }
    __syncthreads();
    float vacc[4][4];
#pragma unroll
    for (int i = 0; i < 4; ++i)
#pragma unroll
        for (int j = 0; j < 4; ++j) vacc[i][j] = 0.f;
    for (int kk = 0; kk < KT; ++kk) {
        const int src = l0 + lr - (KT - 1 - kk) * dil;
        const bool ok = (src >= 0) && (src < LL);
        tile_gemm_f32(xb, src, ok, Wvh + (size_t)(kk * HW + lr) * DM + k4,
                      lr, k4, tx, ty, As, Ws, acc);
        const float* bvp = bvh + kk * HW + (tx << 2);
#pragma unroll
        for (int i = 0; i < 4; ++i) {
            float sc = lg[(ty << 2) + i][kk];
#pragma unroll
            for (int j = 0; j < 4; ++j)
                vacc[i][j] = fmaf(sc, acc[i][j] + bvp[j], vacc[i][j]);
        }
    }
#pragma unroll
    for (int i = 0; i < 4; ++i) {
        float4 o;
        o.x = vacc[i][0] * 0.125f;
        o.y = vacc[i][1] * 0.125f;
        o.z = vacc[i][2] * 0.125f;
        o.w = vacc[i][3] * 0.125f;
        *(float4*)&attn[((size_t)(b * LL + l0 + (ty << 2) + i) * HH + h) * HW + (tx << 2)] = o;
    }
}

// ===========================================================================
extern "C" void kernel_launch(void* const* d_in, const int* in_sizes, int n_in,
                              void* d_out, int out_size, void* d_ws, size_t ws_size,
                              hipStream_t stream)
{
    const float* x  = (const float*)d_in[0];
    const float* Wq = (const float*)d_in[1];
    const float* bq = (const float*)d_in[2];
    const float* Wk = (const float*)d_in[3];
    const float* bk = (const float*)d_in[4];
    const float* Wv = (const float*)d_in[5];
    const float* bv = (const float*)d_in[6];
    const float* Wo = (const float*)d_in[7];
    const float* bo = (const float*)d_in[8];
    float* out = (float*)d_out;

    const int M = BD * LL;  // 2048

    // ws layout (ushort elements) for the fast path
    const size_t N_X   = (size_t)BD * LL * DM;            //  1,048,576
    const size_t N_WB  = (size_t)NQKV * DM;               //  8,650,752
    const size_t N_WO  = (size_t)DM * DM;                 //    262,144
    const size_t N_QKV = (size_t)M * NQKV;                // 34,603,008 = qb+kvb
    const size_t NEED  = (N_X + N_WB + N_WO + N_QKV + N_X) * 2;

    if (ws_size >= NEED) {
        u16* xb    = (u16*)d_ws;
        u16* wb    = xb    + N_X;      // [Wq|Wk|Wv] swizzled, 16896 x 512
        u16* wob   = wb    + N_WB;
        u16* qb    = wob   + N_WO;     // q: 2048 x 512
        u16* kvb   = qb    + N_X;      // k/v panels: 512 x 65536
        u16* attnb = qb    + N_QKV;

        cvt_swz<<<4864, 256, 0, stream>>>(x, Wq, Wk, Wv, Wo, xb, wb, wob);

        // q/k/v projections (counted-vmcnt 3-buf + setprio, XCD remap)
        gemm_bf16<<<dim3(2112), 256, 0, stream>>>(
            xb, wb, bq, bk, bv, qb, kvb);

        // k-split two-phase gather -> attnb (swizzled); grid B*H*(L/16)
        attn_bf16<<<BD * HH * (LL / 16), 256, 0, stream>>>(
            qb, kvb, bk, bv, attnb);

        // out = attnb * Wo^T + bo -> fp32
        gemm_out<<<dim3(8, 32), 256, 0, stream>>>(attnb, wob, bo, out);
    } else {
        // fp32 fallback (round-1 path, 8 MB ws)
        float* qws = (float*)d_ws;
        float* aws = qws + (size_t)BD * LL * HH * HW;
        gemm_nt_bias<<<dim3((HH * HW) / 64, M / 64), 256, 0, stream>>>(
            x, Wq, bq, qws, M, HH * HW, DM);
        attn_kernel<<<BD * HH * (LL / 64), 256, 0, stream>>>(
            x, qws, Wk, bk, Wv, bv, aws);
        gemm_nt_bias<<<dim3(DM / 64, M / 64), 256, 0, stream>>>(
            aws, Wo, bo, out, M, DM, HH * HW);
    }
}